// Round 6
// baseline (49204.749 us; speedup 1.0000x reference)
//
#include <hip/hip_runtime.h>
#include <hip/hip_bf16.h>
#include <math.h>

// ---------------------------------------------------------------------------
// VRNN on MI355X — Round 9: R8 + non-temporal streaming (weights stay L2-hot).
// R8 diagnosis: per-step streaming (gxx/e1x/exchange/writes) evicted the
// 1.5MB/XCD weight set from L2 every step -> all weight loads were L3-latency
// misses (22MB/step refetch). This round: nt-hints on ALL streaming traffic,
// depth-2 rotation on GRU exchange frags, hoisted epilogue loads, full unroll
// (compile-time rotation idx), faster barrier spin.
// ---------------------------------------------------------------------------

typedef __attribute__((ext_vector_type(8))) short bfrag;   // 8 x bf16
typedef __attribute__((ext_vector_type(4))) short sfrag;   // 4 x bf16 (8B)
typedef __attribute__((ext_vector_type(4))) float ffrag;   // 4 x f32
typedef __hip_bfloat16 bf16;

#define NWG 32

__device__ __forceinline__ float softplus_f(float v) {
    return (v > 20.f) ? v : log1pf(expf(v));
}
__device__ __forceinline__ float sigmoid_f(float v) {
    return 1.f / (1.f + expf(-v));
}
__device__ __forceinline__ short b2s(float x) {
    bf16 t = __float2bfloat16(x);
    return *reinterpret_cast<short*>(&t);
}
__device__ __forceinline__ float s2f(short s) {
    union { unsigned u; float f; } c;
    c.u = ((unsigned)(unsigned short)s) << 16;
    return c.f;
}

// non-temporal access helpers (streaming data must not evict L2-hot weights)
__device__ __forceinline__ bfrag ntl8(const bf16* p) {
    return __builtin_nontemporal_load((const bfrag*)p);
}
__device__ __forceinline__ sfrag ntl4(const bf16* p) {
    return __builtin_nontemporal_load((const sfrag*)p);
}
__device__ __forceinline__ void nts8(bf16* p, bfrag v) {
    __builtin_nontemporal_store(v, (bfrag*)p);
}
__device__ __forceinline__ float ntlf(const float* p) {
    return __builtin_nontemporal_load(p);
}
__device__ __forceinline__ void ntsf(float* p, float v) {
    __builtin_nontemporal_store(v, p);
}
__device__ __forceinline__ void ntss(short* p, short v) {
    __builtin_nontemporal_store(v, p);
}

// Generational grid barrier, device(agent) scope. All NWG WGs co-resident.
__device__ __forceinline__ void grid_barrier(int* bar, int tid) {
    __threadfence();
    __syncthreads();
    if (tid == 0) {
        int gen = __hip_atomic_load(bar + 1, __ATOMIC_RELAXED, __HIP_MEMORY_SCOPE_AGENT);
        int arrived = __hip_atomic_fetch_add(bar, 1, __ATOMIC_ACQ_REL, __HIP_MEMORY_SCOPE_AGENT);
        if (arrived == NWG - 1) {
            __hip_atomic_store(bar, 0, __ATOMIC_RELAXED, __HIP_MEMORY_SCOPE_AGENT);
            __hip_atomic_fetch_add(bar + 1, 1, __ATOMIC_RELEASE, __HIP_MEMORY_SCOPE_AGENT);
        } else {
            while (__hip_atomic_load(bar + 1, __ATOMIC_ACQUIRE, __HIP_MEMORY_SCOPE_AGENT) == gen)
                __builtin_amdgcn_s_sleep(1);
        }
    }
    __syncthreads();
    __threadfence();
}

// ---- setup converters ----
__global__ __launch_bounds__(256) void f2b_kernel(
    const float* __restrict__ s, bf16* __restrict__ d, int n)
{
    int i = blockIdx.x * 256 + threadIdx.x;
    if (i < n) d[i] = __float2bfloat16(s[i]);
}
__global__ __launch_bounds__(256) void fcopy_kernel(
    const float* __restrict__ s, float* __restrict__ d, int n)
{
    int i = blockIdx.x * 256 + threadIdx.x;
    if (i < n) d[i] = s[i];
}

// Pack weight W[n0+t*16+(L&15)][k0+kb*32+(L>>4)*8+j] -> dst[((t*KB+kb)*64+L)*8+j]
__global__ __launch_bounds__(256) void packw_kernel(
    const float* __restrict__ src, bf16* __restrict__ dst,
    int ldw, int n0, int k0, int KB, int total)
{
    int i = blockIdx.x * 256 + threadIdx.x;
    if (i >= total) return;
    const int j = i & 7;
    const int L = (i >> 3) & 63;
    const int r = i >> 9;
    const int kb = r % KB, t = r / KB;
    dst[i] = __float2bfloat16(
        src[(size_t)(n0 + t * 16 + (L & 15)) * ldw + k0 + kb * 32 + ((L >> 4) * 8) + j]);
}

__global__ __launch_bounds__(256) void init_kernel(
    float* __restrict__ hlive, bf16* __restrict__ hh0, int* __restrict__ bar,
    float* __restrict__ out)
{
    const int idx = blockIdx.x * 256 + threadIdx.x;
    if (idx < 262144) { hlive[idx] = 0.f; hh0[idx] = __float2bfloat16(0.f); }
    if (idx < 256) bar[idx] = 0;
    if (idx < 3) out[idx] = 0.f;
}

// ---------------------------------------------------------------------------
// MFMA GEMM (unchanged, verified). act: 0 none, 1 relu, 2 softplus col>=32,
// 3 relu col<64. obf: 0 f32 row-major, 1 bf16 row-major, 2 bf16 packed C-frag.
// ---------------------------------------------------------------------------
__global__ __launch_bounds__(256) void mfma_gemm(
    const bf16* __restrict__ A0, int lda0, const bf16* __restrict__ W0, int ldw0, int K0,
    const bf16* __restrict__ A1, int lda1, const bf16* __restrict__ W1, int ldw1, int K1,
    const float* __restrict__ bias, int act,
    void* __restrict__ C, int ldc, int obf)
{
    const int tid = threadIdx.x;
    const int L = tid & 63, w = tid >> 6;
    const int m0 = blockIdx.y * 64 + (w & 1) * 32;
    const int n0 = blockIdx.x * 64 + (w >> 1) * 32;
    const int lr = L & 15;
    const int lk = (L >> 4) * 8;

    ffrag acc[2][2];
#pragma unroll
    for (int i = 0; i < 2; ++i)
#pragma unroll
        for (int j = 0; j < 2; ++j)
#pragma unroll
            for (int r = 0; r < 4; ++r) acc[i][j][r] = 0.f;

    for (int s = 0; s < 2; ++s) {
        const bf16* A = s ? A1 : A0;
        if (!A) break;
        const bf16* W = s ? W1 : W0;
        const int lda = s ? lda1 : lda0;
        const int ldw = s ? ldw1 : ldw0;
        const int K   = s ? K1 : K0;
        const bf16* a0p = A + (size_t)(m0 + lr) * lda + lk;
        const bf16* a1p = a0p + (size_t)16 * lda;
        const bf16* b0p = W + (size_t)(n0 + lr) * ldw + lk;
        const bf16* b1p = b0p + (size_t)16 * ldw;
        for (int k0 = 0; k0 < K; k0 += 32) {
            bfrag a0 = *(const bfrag*)(a0p + k0);
            bfrag a1 = *(const bfrag*)(a1p + k0);
            bfrag b0 = *(const bfrag*)(b0p + k0);
            bfrag b1 = *(const bfrag*)(b1p + k0);
            acc[0][0] = __builtin_amdgcn_mfma_f32_16x16x32_bf16(a0, b0, acc[0][0], 0, 0, 0);
            acc[0][1] = __builtin_amdgcn_mfma_f32_16x16x32_bf16(a0, b1, acc[0][1], 0, 0, 0);
            acc[1][0] = __builtin_amdgcn_mfma_f32_16x16x32_bf16(a1, b0, acc[1][0], 0, 0, 0);
            acc[1][1] = __builtin_amdgcn_mfma_f32_16x16x32_bf16(a1, b1, acc[1][1], 0, 0, 0);
        }
    }

#pragma unroll
    for (int i = 0; i < 2; ++i)
#pragma unroll
    for (int j = 0; j < 2; ++j)
#pragma unroll
    for (int r = 0; r < 4; ++r) {
        const int row = m0 + 16 * i + (L >> 4) * 4 + r;
        const int col = n0 + 16 * j + lr;
        float v = acc[i][j][r];
        if (bias) v += bias[col];
        if (act == 1) v = fmaxf(v, 0.f);
        else if (act == 2) { if (col >= 32) v = softplus_f(v); }
        else if (act == 3) { if (col < 64) v = fmaxf(v, 0.f); }
        if (obf == 1) {
            ((bf16*)C)[(size_t)row * ldc + col] = __float2bfloat16(v);
        } else if (obf == 2) {
            ((bf16*)C)[((size_t)(row >> 4) * (ldc >> 4) + (col >> 4)) * 256
                       + (size_t)L * 4 + r] = __float2bfloat16(v);
        } else {
            ((float*)C)[(size_t)row * ldc + col] = v;
        }
    }
}

// ---------------------------------------------------------------------------
// Persistent sequential kernel. 32 WGs x 512 thr. Row role (A-C): WG bm owns
// rows 16bm..+16. GRU role: jgroup bm&7 (matches XCD -> 384KB slice resident),
// rowgroup bm>>3. 2 grid barriers/step. Weights cached; streams nt.
// ---------------------------------------------------------------------------
#define AST 536

__global__ __launch_bounds__(512, 1) void seq_kernel(
    const bf16* __restrict__ e1xp,    // packed [TC*32 rt][32 ct][256]
    const bf16* __restrict__ gxxp,    // packed [TC*32 rt][96 ct][256]
    const float* __restrict__ eps_c,  // [TC*512,32]
    const bf16* __restrict__ ew1hp,   // packed (512x512)
    const bf16* __restrict__ ew2p,    // packed (512x512)
    const float* __restrict__ eb2,
    const bf16* __restrict__ mswp,    // packed (64x512)
    const float* __restrict__ msb,    // [64]
    const bf16* __restrict__ pzwp,    // packed (512x32)
    const float* __restrict__ pzb,    // [512]
    const bf16* __restrict__ wihzp,   // packed (1536x512)
    const bf16* __restrict__ whhp,    // packed (1536x512)
    float* __restrict__ hlive,        // [512,512] fp32
    bf16* __restrict__ hh,            // [(TC+1)*512,512]
    float* __restrict__ emsc,         // [TC*512,64]
    bf16* __restrict__ phizc,         // [TC*512,512]
    bf16* __restrict__ pzp,           // packed phi_z a-frags [32 rt][16 kb][512]
    bf16* __restrict__ hpp,           // packed h     a-frags [32 rt][16 kb][512]
    int* __restrict__ bar,
    int TC, int hsrc0)
{
    __shared__ __align__(16) bf16 hB[16][AST];
    __shared__ __align__(16) bf16 p1[16][AST];
    __shared__ __align__(16) bf16 p2[16][AST];
    __shared__ float msd[16][65];
    __shared__ __align__(16) bf16 zb[16][40];

    const int tid = threadIdx.x;
    const int L = tid & 63, w = tid >> 6;       // w in 0..7
    const int lr = L & 15, lk = (L >> 4) * 8;
    const int rq = (L >> 4) * 4;
    const int bm = blockIdx.x;
    const int m0 = bm * 16;

    const int hrow = tid >> 5, hc0 = (tid & 31) * 16;
    const size_t Lo = (size_t)L * 8;

    for (int lt = 0; lt < TC; ++lt) {
        const size_t rb = (size_t)lt * 512 + m0;
        const size_t rt = (size_t)lt * 32 + bm;     // packed row-tile index

        // ---------- load h (bf16 from HH slot) into hB ----------
        {
            const int slot = (lt == 0) ? hsrc0 : lt;
            const bf16* hsv = hh + (size_t)slot * 262144 + (size_t)(m0 + hrow) * 512 + hc0;
            bfrag h0 = ntl8(hsv);
            bfrag h1 = ntl8(hsv + 8);
            *(bfrag*)&hB[hrow][hc0]     = h0;
            *(bfrag*)&hB[hrow][hc0 + 8] = h1;
            if (lt == 0 && hsrc0 != 0) {   // chunk-start h -> slot 0 for post
                bf16* d0 = hh + (size_t)(m0 + hrow) * 512 + hc0;
                nts8(d0, h0);
                nts8(d0 + 8, h1);
            }
        }
        __syncthreads();

        // ---------- dump h a-frags for GRU ----------
#pragma unroll
        for (int q = 0; q < 2; ++q) {
            const int kb = w * 2 + q;
            nts8(hpp + (((size_t)bm * 16 + kb) << 9) + Lo,
                 *(const bfrag*)&hB[lr][kb * 32 + lk]);
        }

        // ---------- stage A: p1 = relu(E1X + h @ eW1h^T) ----------
        {
            sfrag exv[4];
#pragma unroll
            for (int nt = 0; nt < 4; ++nt)
                exv[nt] = ntl4(e1xp + (rt * 32 + 4 * w + nt) * 256 + (size_t)L * 4);

            bfrag wf[4][4];
#pragma unroll
            for (int d = 0; d < 4; ++d)
#pragma unroll
                for (int nt = 0; nt < 4; ++nt)
                    wf[d][nt] = *(const bfrag*)(ew1hp + (((4 * w + nt) * 16 + d) << 9) + Lo);

            ffrag acc[4];
#pragma unroll
            for (int nt = 0; nt < 4; ++nt)
#pragma unroll
                for (int r = 0; r < 4; ++r) acc[nt][r] = 0.f;

#pragma unroll
            for (int kb = 0; kb < 16; ++kb) {
                bfrag a = *(const bfrag*)&hB[lr][kb * 32 + lk];
                const int cur = kb & 3;
#pragma unroll
                for (int nt = 0; nt < 4; ++nt)
                    acc[nt] = __builtin_amdgcn_mfma_f32_16x16x32_bf16(a, wf[cur][nt], acc[nt], 0, 0, 0);
                if (kb < 12)
#pragma unroll
                    for (int nt = 0; nt < 4; ++nt)
                        wf[cur][nt] = *(const bfrag*)(ew1hp + (((4 * w + nt) * 16 + kb + 4) << 9) + Lo);
            }
#pragma unroll
            for (int nt = 0; nt < 4; ++nt)
#pragma unroll
            for (int r = 0; r < 4; ++r) {
                const int row = rq + r, col = 64 * w + 16 * nt + lr;
                float v = acc[nt][r] + s2f(exv[nt][r]);
                p1[row][col] = __float2bfloat16(fmaxf(v, 0.f));
            }
        }
        __syncthreads();

        // ---------- stage B: p2 = relu(p1 @ eW2^T + eb2) ----------
        {
            bfrag wf[4][4];
#pragma unroll
            for (int d = 0; d < 4; ++d)
#pragma unroll
                for (int nt = 0; nt < 4; ++nt)
                    wf[d][nt] = *(const bfrag*)(ew2p + (((4 * w + nt) * 16 + d) << 9) + Lo);

            ffrag acc[4];
#pragma unroll
            for (int nt = 0; nt < 4; ++nt)
#pragma unroll
                for (int r = 0; r < 4; ++r) acc[nt][r] = 0.f;

#pragma unroll
            for (int kb = 0; kb < 16; ++kb) {
                bfrag a = *(const bfrag*)&p1[lr][kb * 32 + lk];
                const int cur = kb & 3;
#pragma unroll
                for (int nt = 0; nt < 4; ++nt)
                    acc[nt] = __builtin_amdgcn_mfma_f32_16x16x32_bf16(a, wf[cur][nt], acc[nt], 0, 0, 0);
                if (kb < 12)
#pragma unroll
                    for (int nt = 0; nt < 4; ++nt)
                        wf[cur][nt] = *(const bfrag*)(ew2p + (((4 * w + nt) * 16 + kb + 4) << 9) + Lo);
            }
#pragma unroll
            for (int nt = 0; nt < 4; ++nt)
#pragma unroll
            for (int r = 0; r < 4; ++r) {
                const int row = rq + r, col = 64 * w + 16 * nt + lr;
                float v = fmaxf(acc[nt][r] + eb2[col], 0.f);
                p2[row][col] = __float2bfloat16(v);
            }
        }
        __syncthreads();

        // ---------- stage C1: ms = p2 @ msw^T + msb (softplus >=32) -------
        if (w < 4) {
            bfrag mf[4];
#pragma unroll
            for (int d = 0; d < 4; ++d)
                mf[d] = *(const bfrag*)(mswp + ((w * 16 + d) << 9) + Lo);
            ffrag acc;
#pragma unroll
            for (int r = 0; r < 4; ++r) acc[r] = 0.f;
#pragma unroll
            for (int kb = 0; kb < 16; ++kb) {
                bfrag a = *(const bfrag*)&p2[lr][kb * 32 + lk];
                const int cur = kb & 3;
                acc = __builtin_amdgcn_mfma_f32_16x16x32_bf16(a, mf[cur], acc, 0, 0, 0);
                if (kb < 12)
                    mf[cur] = *(const bfrag*)(mswp + ((w * 16 + kb + 4) << 9) + Lo);
            }
#pragma unroll
            for (int r = 0; r < 4; ++r) {
                const int row = rq + r, col = 16 * w + lr;
                float v = acc[r] + msb[col];
                if (col >= 32) v = softplus_f(v);
                msd[row][col] = v;
                ntsf(&emsc[(rb + row) * 64 + col], v);
            }
        }
        __syncthreads();

        // ---------- stage C2: z = eps*std + mean (x10 on cols<4) ----------
        {
            const int row = tid >> 5, c = tid & 31;
            float zv = ntlf(&eps_c[(rb + row) * 32 + c]) * msd[row][32 + c] + msd[row][c];
            if (c < 4) zv *= 10.f;
            zb[row][c] = __float2bfloat16(zv);
        }
        __syncthreads();

        // ---------- stage C3: p1 = relu(z @ pzw^T + pzb) ----------
        {
            bfrag a = *(const bfrag*)&zb[lr][lk];
#pragma unroll
            for (int nt = 0; nt < 4; ++nt) {
                const int col = 64 * w + 16 * nt + lr;
                bfrag b = *(const bfrag*)(pzwp + ((4 * w + nt) << 9) + Lo);
                ffrag c_;
#pragma unroll
                for (int r = 0; r < 4; ++r) c_[r] = 0.f;
                c_ = __builtin_amdgcn_mfma_f32_16x16x32_bf16(a, b, c_, 0, 0, 0);
#pragma unroll
                for (int r = 0; r < 4; ++r) {
                    const int row = rq + r;
                    const float v = fmaxf(c_[r] + pzb[col], 0.f);
                    p1[row][col] = __float2bfloat16(v);
                }
            }
        }
        __syncthreads();

        // ---------- dump phi_z: packed a-frags + row-major for post -------
#pragma unroll
        for (int q = 0; q < 2; ++q) {
            const int kb = w * 2 + q;
            nts8(pzp + (((size_t)bm * 16 + kb) << 9) + Lo,
                 *(const bfrag*)&p1[lr][kb * 32 + lk]);
        }
        {
            const int prow = tid >> 5, pc0 = (tid & 31) * 16;
            bf16* pp = phizc + (rb + prow) * 512 + pc0;
            nts8(pp,     *(const bfrag*)&p1[prow][pc0]);
            nts8(pp + 8, *(const bfrag*)&p1[prow][pc0 + 8]);
        }

        grid_barrier(bar, tid);   // phi_z/h a-frags visible device-wide

        // ---------- GRU (column-split, jgroup pinned to XCD) ----------
        {
            const int jj  = ((bm & 7) << 2) + (w & 3);           // j-slice 0..31
            const int rt0 = ((bm >> 3) << 3) + ((w >> 2) << 2);  // 4 rowtiles

            // hoisted epilogue loads (hide L3 latency under the k-loop)
            sfrag gr[4], gz[4], gn[4];
            float hvp[4][4];
#pragma unroll
            for (int r4 = 0; r4 < 4; ++r4) {
                const size_t gb = ((size_t)lt * 32 + rt0 + r4) * 96;
                gr[r4] = ntl4(gxxp + (gb + jj     ) * 256 + (size_t)L * 4);
                gz[r4] = ntl4(gxxp + (gb + jj + 32) * 256 + (size_t)L * 4);
                gn[r4] = ntl4(gxxp + (gb + jj + 64) * 256 + (size_t)L * 4);
#pragma unroll
                for (int r = 0; r < 4; ++r)
                    hvp[r4][r] = hlive[(size_t)((rt0 + r4) * 16 + rq + r) * 512 + jj * 16 + lr];
            }

            // exchange prefetch depth-2
            bfrag azf[2][4], ahf[2][4];
#pragma unroll
            for (int q = 0; q < 2; ++q)
#pragma unroll
                for (int r4 = 0; r4 < 4; ++r4) {
                    const size_t fb = (((size_t)(rt0 + r4) * 16 + q) << 9) + Lo;
                    azf[q][r4] = ntl8(pzp + fb);
                    ahf[q][r4] = ntl8(hpp + fb);
                }

            ffrag sR[4], sZ[4], aN[4], hN[4];
#pragma unroll
            for (int r4 = 0; r4 < 4; ++r4)
#pragma unroll
                for (int r = 0; r < 4; ++r) {
                    sR[r4][r] = 0.f; sZ[r4][r] = 0.f; aN[r4][r] = 0.f; hN[r4][r] = 0.f;
                }

#pragma unroll
            for (int kb = 0; kb < 16; ++kb) {
                const int cur = kb & 1;
                bfrag wzr = *(const bfrag*)(wihzp + (((size_t)(jj     ) * 16 + kb) << 9) + Lo);
                bfrag wzz = *(const bfrag*)(wihzp + (((size_t)(jj + 32) * 16 + kb) << 9) + Lo);
                bfrag wzn = *(const bfrag*)(wihzp + (((size_t)(jj + 64) * 16 + kb) << 9) + Lo);
                bfrag whr = *(const bfrag*)(whhp  + (((size_t)(jj     ) * 16 + kb) << 9) + Lo);
                bfrag whz = *(const bfrag*)(whhp  + (((size_t)(jj + 32) * 16 + kb) << 9) + Lo);
                bfrag whn = *(const bfrag*)(whhp  + (((size_t)(jj + 64) * 16 + kb) << 9) + Lo);
#pragma unroll
                for (int r4 = 0; r4 < 4; ++r4) {
                    sR[r4] = __builtin_amdgcn_mfma_f32_16x16x32_bf16(azf[cur][r4], wzr, sR[r4], 0, 0, 0);
                    sR[r4] = __builtin_amdgcn_mfma_f32_16x16x32_bf16(ahf[cur][r4], whr, sR[r4], 0, 0, 0);
                    sZ[r4] = __builtin_amdgcn_mfma_f32_16x16x32_bf16(azf[cur][r4], wzz, sZ[r4], 0, 0, 0);
                    sZ[r4] = __builtin_amdgcn_mfma_f32_16x16x32_bf16(ahf[cur][r4], whz, sZ[r4], 0, 0, 0);
                    aN[r4] = __builtin_amdgcn_mfma_f32_16x16x32_bf16(azf[cur][r4], wzn, aN[r4], 0, 0, 0);
                    hN[r4] = __builtin_amdgcn_mfma_f32_16x16x32_bf16(ahf[cur][r4], whn, hN[r4], 0, 0, 0);
                }
                if (kb < 14)
#pragma unroll
                    for (int r4 = 0; r4 < 4; ++r4) {
                        const size_t fb = (((size_t)(rt0 + r4) * 16 + kb + 2) << 9) + Lo;
                        azf[cur][r4] = ntl8(pzp + fb);
                        ahf[cur][r4] = ntl8(hpp + fb);
                    }
            }

            bf16* hnx = hh + (size_t)(lt + 1) * 262144;
            const int colg = jj * 16 + lr;
#pragma unroll
            for (int r4 = 0; r4 < 4; ++r4) {
#pragma unroll
                for (int r = 0; r < 4; ++r) {
                    const int row = (rt0 + r4) * 16 + rq + r;
                    const size_t gidx = (size_t)row * 512 + colg;
                    const float rg = sigmoid_f(s2f(gr[r4][r]) + sR[r4][r]);
                    const float zg = sigmoid_f(s2f(gz[r4][r]) + sZ[r4][r]);
                    const float nv = tanhf(s2f(gn[r4][r]) + aN[r4][r] + rg * hN[r4][r]);
                    const float hnew = (1.f - zg) * nv + zg * hvp[r4][r];
                    hlive[gidx] = hnew;               // own (j,rt) tile: no race
                    ntss((short*)&hnx[gidx], b2s(hnew));
                }
            }
        }

        grid_barrier(bar, tid);   // h_new visible before next step's stage A
    }
}

// ---------------------------------------------------------------------------
// KLD (unchanged)
// ---------------------------------------------------------------------------
__global__ __launch_bounds__(256) void kld_kernel(
    const float* __restrict__ emsc, const float* __restrict__ pms,
    float* __restrict__ out)
{
    const size_t p0 = (size_t)blockIdx.x * 1024 + threadIdx.x;
    float acc = 0.f;
#pragma unroll
    for (int rep = 0; rep < 4; ++rep) {
        const size_t p = p0 + (size_t)rep * 256;
        const size_t i = p >> 5; const int c = p & 31;
        const float m1 = emsc[i * 64 + c];
        const float s1 = fmaxf(emsc[i * 64 + 32 + c], 1e-9f);
        const float m2 = pms[i * 64 + c];
        const float s2 = fmaxf(pms[i * 64 + 32 + c], 1e-9f);
        const float dm = m1 - m2;
        acc += 2.f * (logf(s2) - logf(s1)) + (s1 * s1 + dm * dm) / (s2 * s2) - 1.f;
    }
    for (int off = 32; off > 0; off >>= 1) acc += __shfl_down(acc, off);
    __shared__ float tmp[4];
    if ((threadIdx.x & 63) == 0) tmp[threadIdx.x >> 6] = acc;
    __syncthreads();
    if (threadIdx.x == 0)
        atomicAdd(out + 1, 0.5f * (tmp[0] + tmp[1] + tmp[2] + tmp[3]));
}

// ---------------------------------------------------------------------------
// final (unchanged)
// ---------------------------------------------------------------------------
__global__ __launch_bounds__(256) void final_kernel(
    const float* __restrict__ ddc,
    const float* __restrict__ W2,
    const float* __restrict__ b2,
    const float* __restrict__ x,
    float* __restrict__ sums,
    float* __restrict__ outDM)
{
    __shared__ float Dh[32][64];
    __shared__ float W2s[64][65];
    const int tid = threadIdx.x;
    const size_t r0 = (size_t)blockIdx.x * 32;

    for (int i = tid; i < 32 * 64; i += 256)
        Dh[i >> 6][i & 63] = ddc[(r0 + (i >> 6)) * 128 + (i & 63)];
    for (int i = tid; i < 64 * 64; i += 256) W2s[i >> 6][i & 63] = W2[i];
    __syncthreads();

    float rec = 0.f, nll = 0.f;
#pragma unroll
    for (int rep = 0; rep < 8; ++rep) {
        const int idx = rep * 256 + tid;
        const int r = idx >> 6, j = idx & 63;
        float acc = b2[j];
#pragma unroll 8
        for (int k = 0; k < 64; ++k) acc += Dh[r][k] * W2s[j][k];
        const size_t g = (r0 + r) * 64 + j;
        const float xv = x[g];
        const float sd = softplus_f(ddc[(r0 + r) * 128 + 64 + j]);
        outDM[g] = acc;
        const float d = xv - acc;
        rec += d * d;
        nll += logf(sd + 1e-5f) + 0.9189385332046727f + d * d / (2.f * sd * sd);
    }
    for (int off = 32; off > 0; off >>= 1) {
        rec += __shfl_down(rec, off);
        nll += __shfl_down(nll, off);
    }
    __shared__ float rr[4], nn[4];
    if ((tid & 63) == 0) { rr[tid >> 6] = rec; nn[tid >> 6] = nll; }
    __syncthreads();
    if (tid == 0) {
        atomicAdd(sums + 0, rr[0] + rr[1] + rr[2] + rr[3]);
        atomicAdd(sums + 2, nn[0] + nn[1] + nn[2] + nn[3]);
    }
}

// ---------------------------------------------------------------------------

static void gemm(hipStream_t s, int M, int N,
                 const bf16* A0, int lda0, const bf16* W0, int ldw0, int K0,
                 const bf16* A1, int lda1, const bf16* W1, int ldw1, int K1,
                 const float* bias, int act, void* C, int ldc, int obf)
{
    dim3 g(N / 64, M / 64), b(256);
    hipLaunchKernelGGL(mfma_gemm, g, b, 0, s,
                       A0, lda0, W0, ldw0, K0, A1, lda1, W1, ldw1, K1,
                       bias, act, C, ldc, obf);
}

static void f2b(hipStream_t s, const float* src, bf16* dst, int n) {
    hipLaunchKernelGGL(f2b_kernel, dim3((n + 255) / 256), dim3(256), 0, s, src, dst, n);
}
static void fcp(hipStream_t s, const float* src, float* dst, int n) {
    hipLaunchKernelGGL(fcopy_kernel, dim3((n + 255) / 256), dim3(256), 0, s, src, dst, n);
}
static void packw(hipStream_t s, const float* src, __hip_bfloat16* dst,
                  int ldw, int n0, int k0, int KB, int total) {
    hipLaunchKernelGGL(packw_kernel, dim3((total + 255) / 256), dim3(256), 0, s,
                       src, dst, ldw, n0, k0, KB, total);
}

// bf16-weight element offsets within WB (row-major for mfma_gemm)
#define O_PXW1 0
#define O_PXW2 32768
#define O_EW1  311296
#define O_PRW  1130496
#define O_PMSW 1392640
#define O_DW1  1425408
#define O_DW2  1949696
#define O_DDW  2211840
#define O_GWIH 2277376

// packed seq-weight element offsets within WPK
#define P_EW1H 0
#define P_EW2  262144
#define P_MSW  524288
#define P_PZW  557056
#define P_WIHZ 573440
#define P_WHH  1359872

// Walks the SAME offset chain as the layout code (R4 crash lesson).
static size_t ws_needed(int tc) {
    size_t off = 32442368ull + (size_t)(tc + 1) * 524288ull;  // ..BAR + HH
    off += (size_t)tc * 524288ull;   // R1 / E1X
    off += (size_t)tc * 524288ull;   // R2
    off += (size_t)tc * 524288ull;   // PHIZC
    off += (size_t)tc * 131072ull;   // EMSC
    off += (size_t)tc * 262144ull;   // U
    off += (size_t)tc * 1572864ull;  // GXX
    return off;
}

extern "C" void kernel_launch(void* const* d_in, const int* in_sizes, int n_in,
                              void* d_out, int out_size, void* d_ws, size_t ws_size,
                              hipStream_t stream)
{
    const float* x_in   = (const float*)d_in[0];
    const float* eps_in = (const float*)d_in[1];
    const float* pxW1 = (const float*)d_in[2];  const float* pxb1 = (const float*)d_in[3];
    const float* pxW2 = (const float*)d_in[4];  const float* pxb2 = (const float*)d_in[5];
    const float* pzW  = (const float*)d_in[6];  const float* pzb  = (const float*)d_in[7];
    const float* eW1  = (const float*)d_in[8];  const float* eb1  = (const float*)d_in[9];
    const float* eW2  = (const float*)d_in[10]; const float* eb2  = (const float*)d_in[11];
    const float* emW  = (const float*)d_in[12]; const float* emb  = (const float*)d_in[13];
    const float* esW  = (const float*)d_in[14]; const float* esb  = (const float*)d_in[15];
    const float* prW  = (const float*)d_in[16]; const float* prb  = (const float*)d_in[17];
    const float* pmW  = (const float*)d_in[18]; const float* pmb  = (const float*)d_in[19];
    const float* psW  = (const float*)d_in[20]; const float* psb  = (const float*)d_in[21];
    const float* dW1  = (const float*)d_in[22]; const float* db1  = (const float*)d_in[23];
    const float* dW2  = (const float*)d_in[24]; const float* db2  = (const float*)d_in[25];
    const float* dsW  = (const float*)d_in[26]; const float* dsb  = (const float*)d_in[27];
    const float* dmW1 = (const float*)d_in[28]; const float* dmb1 = (const float*)d_in[29];
    const float* dmW2 = (const float*)d_in[30]; const float* dmb2 = (const float*)d_in[31];
    const float* gWih = (const float*)d_in[32]; const float* gWhh = (const float*)d_in[33];

    float* out = (float*)d_out;
    char* ws = (char*)d_ws;

    int TC = 1;
    const int cands[9] = {256, 128, 64, 32, 16, 8, 4, 2, 1};
    for (int i = 0; i < 9; ++i)
        if (ws_needed(cands[i]) <= ws_size) { TC = cands[i]; break; }
    const int NCH = 256 / TC;

    // ---- workspace map ----
    bf16*  WB    = (bf16*)(ws);                         // 9,273,344 B
    float* BB    = (float*)(ws + 9273344ull);           // 1,024 B
    bf16*  WPK   = (bf16*)(ws + 9274368ull);            // 4,292,608 B packed
    bf16*  XBF   = (bf16*)(ws + 13566976ull);           // 16,777,216 B
    float* HLIVE = (float*)(ws + 30344192ull);          // 1,048,576 B
    bf16*  PZP   = (bf16*)(ws + 31392768ull);           // 524,288 B
    bf16*  HPP   = (bf16*)(ws + 31917056ull);           // 524,288 B
    int*   BAR   = (int*) (ws + 32441344ull);           // 1,024 B
    bf16*  HH    = (bf16*)(ws + 32442368ull);           // (TC+1)*524,288 B
    size_t off = 32442368ull + (size_t)(TC + 1) * 524288ull;
    bf16*  R1    = (bf16*)(ws + off); off += (size_t)TC * 524288ull;   // also E1X
    bf16*  R2    = (bf16*)(ws + off); off += (size_t)TC * 524288ull;   // PHIX / DECH
    bf16*  PHIZC = (bf16*)(ws + off); off += (size_t)TC * 524288ull;
    float* EMSC  = (float*)(ws + off); off += (size_t)TC * 131072ull;
    float* U     = (float*)(ws + off); off += (size_t)TC * 262144ull;  // PMS then DDC
    bf16*  GXX   = (bf16*)(ws + off);                   // TC*1,572,864 B

    // ---- setup: conversions + packing ----
    f2b(stream, pxW1, WB + O_PXW1, 32768);
    f2b(stream, pxW2, WB + O_PXW2, 262144);
    f2b(stream, eW1,  WB + O_EW1,  524288);
    f2b(stream, prW,  WB + O_PRW,  262144);
    f2b(stream, pmW,  WB + O_PMSW, 16384);
    f2b(stream, psW,  WB + O_PMSW + 16384, 16384);
    f2b(stream, dW1,  WB + O_DW1,  524288);
    f2b(stream, dW2,  WB + O_DW2,  262144);
    f2b(stream, dmW1, WB + O_DDW,  32768);
    f2b(stream, dsW,  WB + O_DDW + 32768, 32768);
    f2b(stream, gWih, WB + O_GWIH, 1572864);
    f2b(stream, x_in, XBF, 8388608);
    fcp(stream, emb,  BB + 0,   32);
    fcp(stream, esb,  BB + 32,  32);
    fcp(stream, pmb,  BB + 64,  32);
    fcp(stream, psb,  BB + 96,  32);
    fcp(stream, dmb1, BB + 128, 64);
    fcp(stream, dsb,  BB + 192, 64);

    packw(stream, eW1,  WPK + P_EW1H, 1024, 0, 512, 16, 262144);
    packw(stream, eW2,  WPK + P_EW2,   512, 0,   0, 16, 262144);
    packw(stream, emW,  WPK + P_MSW,   512, 0,   0, 16, 16384);
    packw(stream, esW,  WPK + P_MSW + 16384, 512, 0, 0, 16, 16384);
    packw(stream, pzW,  WPK + P_PZW,    32, 0,   0,  1, 16384);
    packw(stream, gWih, WPK + P_WIHZ, 1024, 0, 512, 16, 786432);
    packw(stream, gWhh, WPK + P_WHH,   512, 0,   0, 16, 786432);

    hipLaunchKernelGGL(init_kernel, dim3(1024), dim3(256), 0, stream,
                       HLIVE, HH, BAR, out);

    for (int c = 0; c < NCH; ++c) {
        const int cs = c * TC;
        const int MR = TC * 512;

        // ---- pre: phi_x MLP for the chunk ----
        gemm(stream, MR, 512, XBF + (size_t)cs * 32768, 64, WB + O_PXW1, 64, 64,
             nullptr, 0, nullptr, 0, 0, pxb1, 1, R1, 512, 1);
        gemm(stream, MR, 512, R1, 512, WB + O_PXW2, 512, 512,
             nullptr, 0, nullptr, 0, 0, pxb2, 1, R2, 512, 1);

        // ---- pre: hoisted phi_x contributions (packed C-fragment out) ----
        gemm(stream, MR, 512, R2, 512, WB + O_EW1, 1024, 512,
             nullptr, 0, nullptr, 0, 0, eb1, 0, R1, 512, 2);
        gemm(stream, MR, 1536, R2, 512, WB + O_GWIH, 1024, 512,
             nullptr, 0, nullptr, 0, 0, nullptr, 0, GXX, 1536, 2);

        // ---- the entire TC-step recurrence: ONE launch ----
        hipLaunchKernelGGL(seq_kernel, dim3(NWG), dim3(512), 0, stream,
                           R1, GXX, eps_in + (size_t)cs * 16384,
                           WPK + P_EW1H, WPK + P_EW2, eb2,
                           WPK + P_MSW, BB, WPK + P_PZW, pzb,
                           WPK + P_WIHZ, WPK + P_WHH,
                           HLIVE, HH, EMSC, PHIZC, PZP, HPP, BAR,
                           TC, (c == 0) ? 0 : TC);

        // ---- post: prior + KLD ----
        gemm(stream, MR, 512, HH, 512, WB + O_PRW, 512, 512,
             nullptr, 0, nullptr, 0, 0, prb, 1, R1, 512, 1);
        gemm(stream, MR, 64, R1, 512, WB + O_PMSW, 512, 512,
             nullptr, 0, nullptr, 0, 0, BB + 64, 2, U, 64, 0);
        hipLaunchKernelGGL(kld_kernel, dim3(TC * 16), dim3(256), 0, stream,
                           EMSC, U, out);

        // ---- post: dec + NLL/rec ----
        gemm(stream, MR, 512, PHIZC, 512, WB + O_DW1, 1024, 512,
             HH, 512, WB + O_DW1 + 512, 1024, 512, db1, 1, R1, 512, 1);
        gemm(stream, MR, 512, R1, 512, WB + O_DW2, 512, 512,
             nullptr, 0, nullptr, 0, 0, db2, 1, R2, 512, 1);          // R2: PHIX dead
        gemm(stream, MR, 128, R2, 512, WB + O_DDW, 512, 512,
             nullptr, 0, nullptr, 0, 0, BB + 128, 3, U, 128, 0);
        hipLaunchKernelGGL(final_kernel, dim3(MR / 32), dim3(256), 0, stream,
                           U, dmW2, dmb2, x_in + (size_t)cs * 32768,
                           out, out + 3 + (size_t)cs * 32768);
    }
}

// Round 7
// 11725.295 us; speedup vs baseline: 4.1965x; 4.1965x over previous
//
#include <hip/hip_runtime.h>
#include <hip/hip_bf16.h>
#include <math.h>

// ---------------------------------------------------------------------------
// VRNN on MI355X — Round 10: per-step launches, no fences, packed streams.
// R8/R9 lesson: grid barriers need device-scope fences which writeback/
// invalidate per-XCD L2 every step -> weights can never stay L2-resident in a
// persistent grid-synced kernel; and 32 WGs idles 87% of the chip.
// This round: 2 launches/step (launch boundary = the barrier):
//   encmid (32 WG row-parallel): enc1(+E1X hoist) -> enc2 -> heads -> z ->
//           phi_z, dumps packed a-frags (pzp/hpp) for the GRU.
//   gru    (256 WG column-split): packed weights + packed a-frags + hoisted
//           GXX; writes hlive fp32 + HH[t+1].
// All weight/stream formats are the verified packed-fragment layouts.
// ---------------------------------------------------------------------------

typedef __attribute__((ext_vector_type(8))) short bfrag;   // 8 x bf16
typedef __attribute__((ext_vector_type(4))) short sfrag;   // 4 x bf16 (8B)
typedef __attribute__((ext_vector_type(4))) float ffrag;   // 4 x f32
typedef __hip_bfloat16 bf16;

__device__ __forceinline__ float softplus_f(float v) {
    return (v > 20.f) ? v : log1pf(expf(v));
}
__device__ __forceinline__ float sigmoid_f(float v) {
    return 1.f / (1.f + expf(-v));
}
__device__ __forceinline__ short b2s(float x) {
    bf16 t = __float2bfloat16(x);
    return *reinterpret_cast<short*>(&t);
}
__device__ __forceinline__ float s2f(short s) {
    union { unsigned u; float f; } c;
    c.u = ((unsigned)(unsigned short)s) << 16;
    return c.f;
}

// ---- setup converters ----
__global__ __launch_bounds__(256) void f2b_kernel(
    const float* __restrict__ s, bf16* __restrict__ d, int n)
{
    int i = blockIdx.x * 256 + threadIdx.x;
    if (i < n) d[i] = __float2bfloat16(s[i]);
}
__global__ __launch_bounds__(256) void fcopy_kernel(
    const float* __restrict__ s, float* __restrict__ d, int n)
{
    int i = blockIdx.x * 256 + threadIdx.x;
    if (i < n) d[i] = s[i];
}

// Pack weight W[n0+t*16+(L&15)][k0+kb*32+(L>>4)*8+j] -> dst[((t*KB+kb)*64+L)*8+j]
__global__ __launch_bounds__(256) void packw_kernel(
    const float* __restrict__ src, bf16* __restrict__ dst,
    int ldw, int n0, int k0, int KB, int total)
{
    int i = blockIdx.x * 256 + threadIdx.x;
    if (i >= total) return;
    const int j = i & 7;
    const int L = (i >> 3) & 63;
    const int r = i >> 9;
    const int kb = r % KB, t = r / KB;
    dst[i] = __float2bfloat16(
        src[(size_t)(n0 + t * 16 + (L & 15)) * ldw + k0 + kb * 32 + ((L >> 4) * 8) + j]);
}

__global__ __launch_bounds__(256) void init_kernel(
    float* __restrict__ hlive, bf16* __restrict__ hh0, int* __restrict__ bar,
    float* __restrict__ out)
{
    const int idx = blockIdx.x * 256 + threadIdx.x;
    if (idx < 262144) { hlive[idx] = 0.f; hh0[idx] = __float2bfloat16(0.f); }
    if (idx < 256) bar[idx] = 0;
    if (idx < 3) out[idx] = 0.f;
}

// ---------------------------------------------------------------------------
// MFMA GEMM (unchanged, verified). act: 0 none, 1 relu, 2 softplus col>=32,
// 3 relu col<64. obf: 0 f32 row-major, 1 bf16 row-major, 2 bf16 packed C-frag.
// ---------------------------------------------------------------------------
__global__ __launch_bounds__(256) void mfma_gemm(
    const bf16* __restrict__ A0, int lda0, const bf16* __restrict__ W0, int ldw0, int K0,
    const bf16* __restrict__ A1, int lda1, const bf16* __restrict__ W1, int ldw1, int K1,
    const float* __restrict__ bias, int act,
    void* __restrict__ C, int ldc, int obf)
{
    const int tid = threadIdx.x;
    const int L = tid & 63, w = tid >> 6;
    const int m0 = blockIdx.y * 64 + (w & 1) * 32;
    const int n0 = blockIdx.x * 64 + (w >> 1) * 32;
    const int lr = L & 15;
    const int lk = (L >> 4) * 8;

    ffrag acc[2][2];
#pragma unroll
    for (int i = 0; i < 2; ++i)
#pragma unroll
        for (int j = 0; j < 2; ++j)
#pragma unroll
            for (int r = 0; r < 4; ++r) acc[i][j][r] = 0.f;

    for (int s = 0; s < 2; ++s) {
        const bf16* A = s ? A1 : A0;
        if (!A) break;
        const bf16* W = s ? W1 : W0;
        const int lda = s ? lda1 : lda0;
        const int ldw = s ? ldw1 : ldw0;
        const int K   = s ? K1 : K0;
        const bf16* a0p = A + (size_t)(m0 + lr) * lda + lk;
        const bf16* a1p = a0p + (size_t)16 * lda;
        const bf16* b0p = W + (size_t)(n0 + lr) * ldw + lk;
        const bf16* b1p = b0p + (size_t)16 * ldw;
        for (int k0 = 0; k0 < K; k0 += 32) {
            bfrag a0 = *(const bfrag*)(a0p + k0);
            bfrag a1 = *(const bfrag*)(a1p + k0);
            bfrag b0 = *(const bfrag*)(b0p + k0);
            bfrag b1 = *(const bfrag*)(b1p + k0);
            acc[0][0] = __builtin_amdgcn_mfma_f32_16x16x32_bf16(a0, b0, acc[0][0], 0, 0, 0);
            acc[0][1] = __builtin_amdgcn_mfma_f32_16x16x32_bf16(a0, b1, acc[0][1], 0, 0, 0);
            acc[1][0] = __builtin_amdgcn_mfma_f32_16x16x32_bf16(a1, b0, acc[1][0], 0, 0, 0);
            acc[1][1] = __builtin_amdgcn_mfma_f32_16x16x32_bf16(a1, b1, acc[1][1], 0, 0, 0);
        }
    }

#pragma unroll
    for (int i = 0; i < 2; ++i)
#pragma unroll
    for (int j = 0; j < 2; ++j)
#pragma unroll
    for (int r = 0; r < 4; ++r) {
        const int row = m0 + 16 * i + (L >> 4) * 4 + r;
        const int col = n0 + 16 * j + lr;
        float v = acc[i][j][r];
        if (bias) v += bias[col];
        if (act == 1) v = fmaxf(v, 0.f);
        else if (act == 2) { if (col >= 32) v = softplus_f(v); }
        else if (act == 3) { if (col < 64) v = fmaxf(v, 0.f); }
        if (obf == 1) {
            ((bf16*)C)[(size_t)row * ldc + col] = __float2bfloat16(v);
        } else if (obf == 2) {
            ((bf16*)C)[((size_t)(row >> 4) * (ldc >> 4) + (col >> 4)) * 256
                       + (size_t)L * 4 + r] = __float2bfloat16(v);
        } else {
            ((float*)C)[(size_t)row * ldc + col] = v;
        }
    }
}

// ---------------------------------------------------------------------------
// encmid: ONE step, stages A-C (enc1 + enc2 + heads + z + phi_z).
// 32 WGs x 512 thr; WG bm owns rows [16bm,16bm+16). Verified R8/R9 stage code
// (nt hints reverted). Dumps packed a-frags pzp/hpp for the gru launch.
// ---------------------------------------------------------------------------
#define AST 536

__global__ __launch_bounds__(512, 1) void encmid_kernel(
    const bf16* __restrict__ e1xp,    // packed [TC*32 rt][32 ct][256]
    const float* __restrict__ eps_c,  // [TC*512,32]
    const bf16* __restrict__ ew1hp,   // packed (512x512)
    const bf16* __restrict__ ew2p,    // packed (512x512)
    const float* __restrict__ eb2,
    const bf16* __restrict__ mswp,    // packed (64x512)
    const float* __restrict__ msb,    // [64]
    const bf16* __restrict__ pzwp,    // packed (512x32)
    const float* __restrict__ pzb,    // [512]
    bf16* __restrict__ hh,            // [(TC+1)*512,512]
    float* __restrict__ emsc,         // [TC*512,64]
    bf16* __restrict__ phizc,         // [TC*512,512]
    bf16* __restrict__ pzp,           // packed phi_z a-frags [32 rt][16 kb][512]
    bf16* __restrict__ hpp,           // packed h     a-frags [32 rt][16 kb][512]
    int lt, int hsrc0)
{
    __shared__ __align__(16) bf16 hB[16][AST];
    __shared__ __align__(16) bf16 p1[16][AST];
    __shared__ __align__(16) bf16 p2[16][AST];
    __shared__ float msd[16][65];
    __shared__ __align__(16) bf16 zb[16][40];

    const int tid = threadIdx.x;
    const int L = tid & 63, w = tid >> 6;       // w in 0..7
    const int lr = L & 15, lk = (L >> 4) * 8;
    const int rq = (L >> 4) * 4;
    const int bm = blockIdx.x;
    const int m0 = bm * 16;

    const int hrow = tid >> 5, hc0 = (tid & 31) * 16;
    const size_t Lo = (size_t)L * 8;

    const size_t rb = (size_t)lt * 512 + m0;
    const size_t rt = (size_t)lt * 32 + bm;     // packed row-tile index

    // ---------- load h (bf16 from HH slot) into hB ----------
    {
        const int slot = (lt == 0) ? hsrc0 : lt;
        const bf16* hsv = hh + (size_t)slot * 262144 + (size_t)(m0 + hrow) * 512 + hc0;
        bfrag h0 = *(const bfrag*)(hsv);
        bfrag h1 = *(const bfrag*)(hsv + 8);
        *(bfrag*)&hB[hrow][hc0]     = h0;
        *(bfrag*)&hB[hrow][hc0 + 8] = h1;
        if (lt == 0 && hsrc0 != 0) {   // chunk-start h -> slot 0 for post
            bf16* d0 = hh + (size_t)(m0 + hrow) * 512 + hc0;
            *(bfrag*)(d0)     = h0;
            *(bfrag*)(d0 + 8) = h1;
        }
    }
    __syncthreads();

    // ---------- dump h a-frags for gru launch ----------
#pragma unroll
    for (int q = 0; q < 2; ++q) {
        const int kb = w * 2 + q;
        *(bfrag*)(hpp + (((size_t)bm * 16 + kb) << 9) + Lo) =
            *(const bfrag*)&hB[lr][kb * 32 + lk];
    }

    // ---------- stage A: p1 = relu(E1X + h @ eW1h^T) ----------
    {
        sfrag exv[4];
#pragma unroll
        for (int nt = 0; nt < 4; ++nt)
            exv[nt] = *(const sfrag*)(e1xp + (rt * 32 + 4 * w + nt) * 256 + (size_t)L * 4);

        bfrag wf[4][4];
#pragma unroll
        for (int d = 0; d < 4; ++d)
#pragma unroll
            for (int nt = 0; nt < 4; ++nt)
                wf[d][nt] = *(const bfrag*)(ew1hp + (((4 * w + nt) * 16 + d) << 9) + Lo);

        ffrag acc[4];
#pragma unroll
        for (int nt = 0; nt < 4; ++nt)
#pragma unroll
            for (int r = 0; r < 4; ++r) acc[nt][r] = 0.f;

#pragma unroll
        for (int kb = 0; kb < 16; ++kb) {
            bfrag a = *(const bfrag*)&hB[lr][kb * 32 + lk];
            const int cur = kb & 3;
#pragma unroll
            for (int nt = 0; nt < 4; ++nt)
                acc[nt] = __builtin_amdgcn_mfma_f32_16x16x32_bf16(a, wf[cur][nt], acc[nt], 0, 0, 0);
            if (kb < 12)
#pragma unroll
                for (int nt = 0; nt < 4; ++nt)
                    wf[cur][nt] = *(const bfrag*)(ew1hp + (((4 * w + nt) * 16 + kb + 4) << 9) + Lo);
        }
#pragma unroll
        for (int nt = 0; nt < 4; ++nt)
#pragma unroll
        for (int r = 0; r < 4; ++r) {
            const int row = rq + r, col = 64 * w + 16 * nt + lr;
            float v = acc[nt][r] + s2f(exv[nt][r]);
            p1[row][col] = __float2bfloat16(fmaxf(v, 0.f));
        }
    }
    __syncthreads();

    // ---------- stage B: p2 = relu(p1 @ eW2^T + eb2) ----------
    {
        bfrag wf[4][4];
#pragma unroll
        for (int d = 0; d < 4; ++d)
#pragma unroll
            for (int nt = 0; nt < 4; ++nt)
                wf[d][nt] = *(const bfrag*)(ew2p + (((4 * w + nt) * 16 + d) << 9) + Lo);

        ffrag acc[4];
#pragma unroll
        for (int nt = 0; nt < 4; ++nt)
#pragma unroll
            for (int r = 0; r < 4; ++r) acc[nt][r] = 0.f;

#pragma unroll
        for (int kb = 0; kb < 16; ++kb) {
            bfrag a = *(const bfrag*)&p1[lr][kb * 32 + lk];
            const int cur = kb & 3;
#pragma unroll
            for (int nt = 0; nt < 4; ++nt)
                acc[nt] = __builtin_amdgcn_mfma_f32_16x16x32_bf16(a, wf[cur][nt], acc[nt], 0, 0, 0);
            if (kb < 12)
#pragma unroll
                for (int nt = 0; nt < 4; ++nt)
                    wf[cur][nt] = *(const bfrag*)(ew2p + (((4 * w + nt) * 16 + kb + 4) << 9) + Lo);
        }
#pragma unroll
        for (int nt = 0; nt < 4; ++nt)
#pragma unroll
        for (int r = 0; r < 4; ++r) {
            const int row = rq + r, col = 64 * w + 16 * nt + lr;
            float v = fmaxf(acc[nt][r] + eb2[col], 0.f);
            p2[row][col] = __float2bfloat16(v);
        }
    }
    __syncthreads();

    // ---------- stage C1: ms = p2 @ msw^T + msb (softplus >=32) -------
    if (w < 4) {
        bfrag mf[4];
#pragma unroll
        for (int d = 0; d < 4; ++d)
            mf[d] = *(const bfrag*)(mswp + ((w * 16 + d) << 9) + Lo);
        ffrag acc;
#pragma unroll
        for (int r = 0; r < 4; ++r) acc[r] = 0.f;
#pragma unroll
        for (int kb = 0; kb < 16; ++kb) {
            bfrag a = *(const bfrag*)&p2[lr][kb * 32 + lk];
            const int cur = kb & 3;
            acc = __builtin_amdgcn_mfma_f32_16x16x32_bf16(a, mf[cur], acc, 0, 0, 0);
            if (kb < 12)
                mf[cur] = *(const bfrag*)(mswp + ((w * 16 + kb + 4) << 9) + Lo);
        }
#pragma unroll
        for (int r = 0; r < 4; ++r) {
            const int row = rq + r, col = 16 * w + lr;
            float v = acc[r] + msb[col];
            if (col >= 32) v = softplus_f(v);
            msd[row][col] = v;
            emsc[(rb + row) * 64 + col] = v;
        }
    }
    __syncthreads();

    // ---------- stage C2: z = eps*std + mean (x10 on cols<4) ----------
    {
        const int row = tid >> 5, c = tid & 31;
        float zv = eps_c[(rb + row) * 32 + c] * msd[row][32 + c] + msd[row][c];
        if (c < 4) zv *= 10.f;
        zb[row][c] = __float2bfloat16(zv);
    }
    __syncthreads();

    // ---------- stage C3: p1 = relu(z @ pzw^T + pzb) ----------
    {
        bfrag a = *(const bfrag*)&zb[lr][lk];
#pragma unroll
        for (int nt = 0; nt < 4; ++nt) {
            const int col = 64 * w + 16 * nt + lr;
            bfrag b = *(const bfrag*)(pzwp + ((4 * w + nt) << 9) + Lo);
            ffrag c_;
#pragma unroll
            for (int r = 0; r < 4; ++r) c_[r] = 0.f;
            c_ = __builtin_amdgcn_mfma_f32_16x16x32_bf16(a, b, c_, 0, 0, 0);
#pragma unroll
            for (int r = 0; r < 4; ++r) {
                const int row = rq + r;
                const float v = fmaxf(c_[r] + pzb[col], 0.f);
                p1[row][col] = __float2bfloat16(v);
            }
        }
    }
    __syncthreads();

    // ---------- dump phi_z: packed a-frags + row-major for post -------
#pragma unroll
    for (int q = 0; q < 2; ++q) {
        const int kb = w * 2 + q;
        *(bfrag*)(pzp + (((size_t)bm * 16 + kb) << 9) + Lo) =
            *(const bfrag*)&p1[lr][kb * 32 + lk];
    }
    {
        const int prow = tid >> 5, pc0 = (tid & 31) * 16;
        bf16* pp = phizc + (rb + prow) * 512 + pc0;
        *(bfrag*)(pp)     = *(const bfrag*)&p1[prow][pc0];
        *(bfrag*)(pp + 8) = *(const bfrag*)&p1[prow][pc0 + 8];
    }
}

// ---------------------------------------------------------------------------
// gru: ONE step, column-split. grid (32 jt, 8 rg) x 256 thr (4 waves).
// Wave w: rowtile rt = rg*4+w, j-tile jt. Packed weights + packed a-frags +
// hoisted GXX. Writes hlive fp32 + HH[t+1] bf16.
// ---------------------------------------------------------------------------
__global__ __launch_bounds__(256) void gru_kernel(
    const bf16* __restrict__ gxxp,    // packed [TC*32 rt][96 ct][256]
    const bf16* __restrict__ wihzp,   // packed (1536x512)
    const bf16* __restrict__ whhp,    // packed (1536x512)
    const bf16* __restrict__ pzp,     // packed phi_z a-frags
    const bf16* __restrict__ hpp,     // packed h a-frags
    float* __restrict__ hlive,        // [512,512] fp32
    bf16* __restrict__ hnx,           // HH slot lt+1
    int lt)
{
    const int tid = threadIdx.x;
    const int L = tid & 63, w = tid >> 6;       // w in 0..3
    const int lr = L & 15;
    const int rq = (L >> 4) * 4;
    const int jt = blockIdx.x;                  // 0..31
    const int rt = blockIdx.y * 4 + w;          // 0..31
    const size_t Lo = (size_t)L * 8;

    // depth-2 rotated streams
    bfrag wz[2][3], wh[2][3], az2[2], ah2[2];
#pragma unroll
    for (int q = 0; q < 2; ++q) {
#pragma unroll
        for (int g = 0; g < 3; ++g) {
            wz[q][g] = *(const bfrag*)(wihzp + (((size_t)(jt + 32 * g) * 16 + q) << 9) + Lo);
            wh[q][g] = *(const bfrag*)(whhp  + (((size_t)(jt + 32 * g) * 16 + q) << 9) + Lo);
        }
        az2[q] = *(const bfrag*)(pzp + (((size_t)rt * 16 + q) << 9) + Lo);
        ah2[q] = *(const bfrag*)(hpp + (((size_t)rt * 16 + q) << 9) + Lo);
    }

    ffrag sR, sZ, aN, hN;
#pragma unroll
    for (int r = 0; r < 4; ++r) { sR[r] = 0.f; sZ[r] = 0.f; aN[r] = 0.f; hN[r] = 0.f; }

#pragma unroll
    for (int kb = 0; kb < 16; ++kb) {
        const int cur = kb & 1;
        sR = __builtin_amdgcn_mfma_f32_16x16x32_bf16(az2[cur], wz[cur][0], sR, 0, 0, 0);
        sR = __builtin_amdgcn_mfma_f32_16x16x32_bf16(ah2[cur], wh[cur][0], sR, 0, 0, 0);
        sZ = __builtin_amdgcn_mfma_f32_16x16x32_bf16(az2[cur], wz[cur][1], sZ, 0, 0, 0);
        sZ = __builtin_amdgcn_mfma_f32_16x16x32_bf16(ah2[cur], wh[cur][1], sZ, 0, 0, 0);
        aN = __builtin_amdgcn_mfma_f32_16x16x32_bf16(az2[cur], wz[cur][2], aN, 0, 0, 0);
        hN = __builtin_amdgcn_mfma_f32_16x16x32_bf16(ah2[cur], wh[cur][2], hN, 0, 0, 0);
        if (kb < 14) {
#pragma unroll
            for (int g = 0; g < 3; ++g) {
                wz[cur][g] = *(const bfrag*)(wihzp + (((size_t)(jt + 32 * g) * 16 + kb + 2) << 9) + Lo);
                wh[cur][g] = *(const bfrag*)(whhp  + (((size_t)(jt + 32 * g) * 16 + kb + 2) << 9) + Lo);
            }
            az2[cur] = *(const bfrag*)(pzp + (((size_t)rt * 16 + kb + 2) << 9) + Lo);
            ah2[cur] = *(const bfrag*)(hpp + (((size_t)rt * 16 + kb + 2) << 9) + Lo);
        }
    }

    // epilogue
    const size_t gb = ((size_t)lt * 32 + rt) * 96;
    sfrag gr = *(const sfrag*)(gxxp + (gb + jt     ) * 256 + (size_t)L * 4);
    sfrag gz = *(const sfrag*)(gxxp + (gb + jt + 32) * 256 + (size_t)L * 4);
    sfrag gn = *(const sfrag*)(gxxp + (gb + jt + 64) * 256 + (size_t)L * 4);
    const int colg = jt * 16 + lr;
#pragma unroll
    for (int r = 0; r < 4; ++r) {
        const int row = rt * 16 + rq + r;
        const size_t gidx = (size_t)row * 512 + colg;
        const float rg = sigmoid_f(s2f(gr[r]) + sR[r]);
        const float zg = sigmoid_f(s2f(gz[r]) + sZ[r]);
        const float nv = tanhf(s2f(gn[r]) + aN[r] + rg * hN[r]);
        const float hv = hlive[gidx];
        const float hnew = (1.f - zg) * nv + zg * hv;
        hlive[gidx] = hnew;
        hnx[gidx] = __float2bfloat16(hnew);
    }
}

// ---------------------------------------------------------------------------
// KLD (unchanged)
// ---------------------------------------------------------------------------
__global__ __launch_bounds__(256) void kld_kernel(
    const float* __restrict__ emsc, const float* __restrict__ pms,
    float* __restrict__ out)
{
    const size_t p0 = (size_t)blockIdx.x * 1024 + threadIdx.x;
    float acc = 0.f;
#pragma unroll
    for (int rep = 0; rep < 4; ++rep) {
        const size_t p = p0 + (size_t)rep * 256;
        const size_t i = p >> 5; const int c = p & 31;
        const float m1 = emsc[i * 64 + c];
        const float s1 = fmaxf(emsc[i * 64 + 32 + c], 1e-9f);
        const float m2 = pms[i * 64 + c];
        const float s2 = fmaxf(pms[i * 64 + 32 + c], 1e-9f);
        const float dm = m1 - m2;
        acc += 2.f * (logf(s2) - logf(s1)) + (s1 * s1 + dm * dm) / (s2 * s2) - 1.f;
    }
    for (int off = 32; off > 0; off >>= 1) acc += __shfl_down(acc, off);
    __shared__ float tmp[4];
    if ((threadIdx.x & 63) == 0) tmp[threadIdx.x >> 6] = acc;
    __syncthreads();
    if (threadIdx.x == 0)
        atomicAdd(out + 1, 0.5f * (tmp[0] + tmp[1] + tmp[2] + tmp[3]));
}

// ---------------------------------------------------------------------------
// final (unchanged)
// ---------------------------------------------------------------------------
__global__ __launch_bounds__(256) void final_kernel(
    const float* __restrict__ ddc,
    const float* __restrict__ W2,
    const float* __restrict__ b2,
    const float* __restrict__ x,
    float* __restrict__ sums,
    float* __restrict__ outDM)
{
    __shared__ float Dh[32][64];
    __shared__ float W2s[64][65];
    const int tid = threadIdx.x;
    const size_t r0 = (size_t)blockIdx.x * 32;

    for (int i = tid; i < 32 * 64; i += 256)
        Dh[i >> 6][i & 63] = ddc[(r0 + (i >> 6)) * 128 + (i & 63)];
    for (int i = tid; i < 64 * 64; i += 256) W2s[i >> 6][i & 63] = W2[i];
    __syncthreads();

    float rec = 0.f, nll = 0.f;
#pragma unroll
    for (int rep = 0; rep < 8; ++rep) {
        const int idx = rep * 256 + tid;
        const int r = idx >> 6, j = idx & 63;
        float acc = b2[j];
#pragma unroll 8
        for (int k = 0; k < 64; ++k) acc += Dh[r][k] * W2s[j][k];
        const size_t g = (r0 + r) * 64 + j;
        const float xv = x[g];
        const float sd = softplus_f(ddc[(r0 + r) * 128 + 64 + j]);
        outDM[g] = acc;
        const float d = xv - acc;
        rec += d * d;
        nll += logf(sd + 1e-5f) + 0.9189385332046727f + d * d / (2.f * sd * sd);
    }
    for (int off = 32; off > 0; off >>= 1) {
        rec += __shfl_down(rec, off);
        nll += __shfl_down(nll, off);
    }
    __shared__ float rr[4], nn[4];
    if ((tid & 63) == 0) { rr[tid >> 6] = rec; nn[tid >> 6] = nll; }
    __syncthreads();
    if (tid == 0) {
        atomicAdd(sums + 0, rr[0] + rr[1] + rr[2] + rr[3]);
        atomicAdd(sums + 2, nn[0] + nn[1] + nn[2] + nn[3]);
    }
}

// ---------------------------------------------------------------------------

static void gemm(hipStream_t s, int M, int N,
                 const bf16* A0, int lda0, const bf16* W0, int ldw0, int K0,
                 const bf16* A1, int lda1, const bf16* W1, int ldw1, int K1,
                 const float* bias, int act, void* C, int ldc, int obf)
{
    dim3 g(N / 64, M / 64), b(256);
    hipLaunchKernelGGL(mfma_gemm, g, b, 0, s,
                       A0, lda0, W0, ldw0, K0, A1, lda1, W1, ldw1, K1,
                       bias, act, C, ldc, obf);
}

static void f2b(hipStream_t s, const float* src, bf16* dst, int n) {
    hipLaunchKernelGGL(f2b_kernel, dim3((n + 255) / 256), dim3(256), 0, s, src, dst, n);
}
static void fcp(hipStream_t s, const float* src, float* dst, int n) {
    hipLaunchKernelGGL(fcopy_kernel, dim3((n + 255) / 256), dim3(256), 0, s, src, dst, n);
}
static void packw(hipStream_t s, const float* src, __hip_bfloat16* dst,
                  int ldw, int n0, int k0, int KB, int total) {
    hipLaunchKernelGGL(packw_kernel, dim3((total + 255) / 256), dim3(256), 0, s,
                       src, dst, ldw, n0, k0, KB, total);
}

// bf16-weight element offsets within WB (row-major for mfma_gemm)
#define O_PXW1 0
#define O_PXW2 32768
#define O_EW1  311296
#define O_PRW  1130496
#define O_PMSW 1392640
#define O_DW1  1425408
#define O_DW2  1949696
#define O_DDW  2211840
#define O_GWIH 2277376

// packed seq-weight element offsets within WPK
#define P_EW1H 0
#define P_EW2  262144
#define P_MSW  524288
#define P_PZW  557056
#define P_WIHZ 573440
#define P_WHH  1359872

// Walks the SAME offset chain as the layout code (R4 crash lesson).
static size_t ws_needed(int tc) {
    size_t off = 32442368ull + (size_t)(tc + 1) * 524288ull;  // ..BAR + HH
    off += (size_t)tc * 524288ull;   // R1 / E1X
    off += (size_t)tc * 524288ull;   // R2
    off += (size_t)tc * 524288ull;   // PHIZC
    off += (size_t)tc * 131072ull;   // EMSC
    off += (size_t)tc * 262144ull;   // U
    off += (size_t)tc * 1572864ull;  // GXX
    return off;
}

extern "C" void kernel_launch(void* const* d_in, const int* in_sizes, int n_in,
                              void* d_out, int out_size, void* d_ws, size_t ws_size,
                              hipStream_t stream)
{
    const float* x_in   = (const float*)d_in[0];
    const float* eps_in = (const float*)d_in[1];
    const float* pxW1 = (const float*)d_in[2];  const float* pxb1 = (const float*)d_in[3];
    const float* pxW2 = (const float*)d_in[4];  const float* pxb2 = (const float*)d_in[5];
    const float* pzW  = (const float*)d_in[6];  const float* pzb  = (const float*)d_in[7];
    const float* eW1  = (const float*)d_in[8];  const float* eb1  = (const float*)d_in[9];
    const float* eW2  = (const float*)d_in[10]; const float* eb2  = (const float*)d_in[11];
    const float* emW  = (const float*)d_in[12]; const float* emb  = (const float*)d_in[13];
    const float* esW  = (const float*)d_in[14]; const float* esb  = (const float*)d_in[15];
    const float* prW  = (const float*)d_in[16]; const float* prb  = (const float*)d_in[17];
    const float* pmW  = (const float*)d_in[18]; const float* pmb  = (const float*)d_in[19];
    const float* psW  = (const float*)d_in[20]; const float* psb  = (const float*)d_in[21];
    const float* dW1  = (const float*)d_in[22]; const float* db1  = (const float*)d_in[23];
    const float* dW2  = (const float*)d_in[24]; const float* db2  = (const float*)d_in[25];
    const float* dsW  = (const float*)d_in[26]; const float* dsb  = (const float*)d_in[27];
    const float* dmW1 = (const float*)d_in[28]; const float* dmb1 = (const float*)d_in[29];
    const float* dmW2 = (const float*)d_in[30]; const float* dmb2 = (const float*)d_in[31];
    const float* gWih = (const float*)d_in[32]; const float* gWhh = (const float*)d_in[33];

    float* out = (float*)d_out;
    char* ws = (char*)d_ws;

    int TC = 1;
    const int cands[9] = {256, 128, 64, 32, 16, 8, 4, 2, 1};
    for (int i = 0; i < 9; ++i)
        if (ws_needed(cands[i]) <= ws_size) { TC = cands[i]; break; }
    const int NCH = 256 / TC;

    // ---- workspace map ----
    bf16*  WB    = (bf16*)(ws);                         // 9,273,344 B
    float* BB    = (float*)(ws + 9273344ull);           // 1,024 B
    bf16*  WPK   = (bf16*)(ws + 9274368ull);            // 4,292,608 B packed
    bf16*  XBF   = (bf16*)(ws + 13566976ull);           // 16,777,216 B
    float* HLIVE = (float*)(ws + 30344192ull);          // 1,048,576 B
    bf16*  PZP   = (bf16*)(ws + 31392768ull);           // 524,288 B
    bf16*  HPP   = (bf16*)(ws + 31917056ull);           // 524,288 B
    int*   BAR   = (int*) (ws + 32441344ull);           // 1,024 B (init only)
    bf16*  HH    = (bf16*)(ws + 32442368ull);           // (TC+1)*524,288 B
    size_t off = 32442368ull + (size_t)(TC + 1) * 524288ull;
    bf16*  R1    = (bf16*)(ws + off); off += (size_t)TC * 524288ull;   // also E1X
    bf16*  R2    = (bf16*)(ws + off); off += (size_t)TC * 524288ull;   // PHIX / DECH
    bf16*  PHIZC = (bf16*)(ws + off); off += (size_t)TC * 524288ull;
    float* EMSC  = (float*)(ws + off); off += (size_t)TC * 131072ull;
    float* U     = (float*)(ws + off); off += (size_t)TC * 262144ull;  // PMS then DDC
    bf16*  GXX   = (bf16*)(ws + off);                   // TC*1,572,864 B

    // ---- setup: conversions + packing ----
    f2b(stream, pxW1, WB + O_PXW1, 32768);
    f2b(stream, pxW2, WB + O_PXW2, 262144);
    f2b(stream, eW1,  WB + O_EW1,  524288);
    f2b(stream, prW,  WB + O_PRW,  262144);
    f2b(stream, pmW,  WB + O_PMSW, 16384);
    f2b(stream, psW,  WB + O_PMSW + 16384, 16384);
    f2b(stream, dW1,  WB + O_DW1,  524288);
    f2b(stream, dW2,  WB + O_DW2,  262144);
    f2b(stream, dmW1, WB + O_DDW,  32768);
    f2b(stream, dsW,  WB + O_DDW + 32768, 32768);
    f2b(stream, gWih, WB + O_GWIH, 1572864);
    f2b(stream, x_in, XBF, 8388608);
    fcp(stream, emb,  BB + 0,   32);
    fcp(stream, esb,  BB + 32,  32);
    fcp(stream, pmb,  BB + 64,  32);
    fcp(stream, psb,  BB + 96,  32);
    fcp(stream, dmb1, BB + 128, 64);
    fcp(stream, dsb,  BB + 192, 64);

    packw(stream, eW1,  WPK + P_EW1H, 1024, 0, 512, 16, 262144);
    packw(stream, eW2,  WPK + P_EW2,   512, 0,   0, 16, 262144);
    packw(stream, emW,  WPK + P_MSW,   512, 0,   0, 16, 16384);
    packw(stream, esW,  WPK + P_MSW + 16384, 512, 0, 0, 16, 16384);
    packw(stream, pzW,  WPK + P_PZW,    32, 0,   0,  1, 16384);
    packw(stream, gWih, WPK + P_WIHZ, 1024, 0, 512, 16, 786432);
    packw(stream, gWhh, WPK + P_WHH,   512, 0,   0, 16, 786432);

    hipLaunchKernelGGL(init_kernel, dim3(1024), dim3(256), 0, stream,
                       HLIVE, HH, BAR, out);

    for (int c = 0; c < NCH; ++c) {
        const int cs = c * TC;
        const int MR = TC * 512;

        // ---- pre: phi_x MLP for the chunk ----
        gemm(stream, MR, 512, XBF + (size_t)cs * 32768, 64, WB + O_PXW1, 64, 64,
             nullptr, 0, nullptr, 0, 0, pxb1, 1, R1, 512, 1);
        gemm(stream, MR, 512, R1, 512, WB + O_PXW2, 512, 512,
             nullptr, 0, nullptr, 0, 0, pxb2, 1, R2, 512, 1);

        // ---- pre: hoisted phi_x contributions (packed C-fragment out) ----
        gemm(stream, MR, 512, R2, 512, WB + O_EW1, 1024, 512,
             nullptr, 0, nullptr, 0, 0, eb1, 0, R1, 512, 2);
        gemm(stream, MR, 1536, R2, 512, WB + O_GWIH, 1024, 512,
             nullptr, 0, nullptr, 0, 0, nullptr, 0, GXX, 1536, 2);

        // ---- sequential steps: 2 launches each, no fences ----
        for (int lt = 0; lt < TC; ++lt) {
            hipLaunchKernelGGL(encmid_kernel, dim3(32), dim3(512), 0, stream,
                               R1, eps_in + (size_t)cs * 16384,
                               WPK + P_EW1H, WPK + P_EW2, eb2,
                               WPK + P_MSW, BB, WPK + P_PZW, pzb,
                               HH, EMSC, PHIZC, PZP, HPP,
                               lt, (c == 0) ? 0 : TC);
            hipLaunchKernelGGL(gru_kernel, dim3(32, 8), dim3(256), 0, stream,
                               GXX, WPK + P_WIHZ, WPK + P_WHH, PZP, HPP,
                               HLIVE, HH + (size_t)(lt + 1) * 262144, lt);
        }

        // ---- post: prior + KLD ----
        gemm(stream, MR, 512, HH, 512, WB + O_PRW, 512, 512,
             nullptr, 0, nullptr, 0, 0, prb, 1, R1, 512, 1);
        gemm(stream, MR, 64, R1, 512, WB + O_PMSW, 512, 512,
             nullptr, 0, nullptr, 0, 0, BB + 64, 2, U, 64, 0);
        hipLaunchKernelGGL(kld_kernel, dim3(TC * 16), dim3(256), 0, stream,
                           EMSC, U, out);

        // ---- post: dec + NLL/rec ----
        gemm(stream, MR, 512, PHIZC, 512, WB + O_DW1, 1024, 512,
             HH, 512, WB + O_DW1 + 512, 1024, 512, db1, 1, R1, 512, 1);
        gemm(stream, MR, 512, R1, 512, WB + O_DW2, 512, 512,
             nullptr, 0, nullptr, 0, 0, db2, 1, R2, 512, 1);          // R2: PHIX dead
        gemm(stream, MR, 128, R2, 512, WB + O_DDW, 512, 512,
             nullptr, 0, nullptr, 0, 0, BB + 128, 3, U, 128, 0);
        hipLaunchKernelGGL(final_kernel, dim3(MR / 32), dim3(256), 0, stream,
                           U, dmW2, dmb2, x_in + (size_t)cs * 32768,
                           out, out + 3 + (size_t)cs * 32768);
    }
}

// Round 8
// 8799.239 us; speedup vs baseline: 5.5919x; 1.3325x over previous
//
#include <hip/hip_runtime.h>
#include <hip/hip_bf16.h>
#include <math.h>

// ---------------------------------------------------------------------------
// VRNN on MI355X — Round 11: R10 + packed/LDS-staged batched GEMM (gemm_p).
// R10 (11.7ms) split ~5.2ms seq + ~6.5ms pre/post. The old mfma_gemm's A and
// B fragment loads were 16-line gathers (64 requests / 4 MFMAs). gemm_p:
// B = packed fragment streams (1 coalesced 1KB wave-load, L2-hot),
// A = LDS-staged 64-col K-panels (coalesced 128B row loads, double-buffered).
// Seq path (encmid/gru) is the verified R10 code, unchanged.
// ---------------------------------------------------------------------------

typedef __attribute__((ext_vector_type(8))) short bfrag;   // 8 x bf16
typedef __attribute__((ext_vector_type(4))) short sfrag;   // 4 x bf16 (8B)
typedef __attribute__((ext_vector_type(4))) float ffrag;   // 4 x f32
typedef __hip_bfloat16 bf16;

__device__ __forceinline__ float softplus_f(float v) {
    return (v > 20.f) ? v : log1pf(expf(v));
}
__device__ __forceinline__ float sigmoid_f(float v) {
    return 1.f / (1.f + expf(-v));
}
__device__ __forceinline__ float s2f(short s) {
    union { unsigned u; float f; } c;
    c.u = ((unsigned)(unsigned short)s) << 16;
    return c.f;
}

// ---- setup converters ----
__global__ __launch_bounds__(256) void f2b_kernel(
    const float* __restrict__ s, bf16* __restrict__ d, int n)
{
    int i = blockIdx.x * 256 + threadIdx.x;
    if (i < n) d[i] = __float2bfloat16(s[i]);
}
__global__ __launch_bounds__(256) void fcopy_kernel(
    const float* __restrict__ s, float* __restrict__ d, int n)
{
    int i = blockIdx.x * 256 + threadIdx.x;
    if (i < n) d[i] = s[i];
}

// Pack weight W[n0+t*16+(L&15)][k0+kb*32+(L>>4)*8+j] -> dst[((t*KB+kb)*64+L)*8+j]
__global__ __launch_bounds__(256) void packw_kernel(
    const float* __restrict__ src, bf16* __restrict__ dst,
    int ldw, int n0, int k0, int KB, int total)
{
    int i = blockIdx.x * 256 + threadIdx.x;
    if (i >= total) return;
    const int j = i & 7;
    const int L = (i >> 3) & 63;
    const int r = i >> 9;
    const int kb = r % KB, t = r / KB;
    dst[i] = __float2bfloat16(
        src[(size_t)(n0 + t * 16 + (L & 15)) * ldw + k0 + kb * 32 + ((L >> 4) * 8) + j]);
}

__global__ __launch_bounds__(256) void init_kernel(
    float* __restrict__ hlive, bf16* __restrict__ hh0, float* __restrict__ out)
{
    const int idx = blockIdx.x * 256 + threadIdx.x;
    if (idx < 262144) { hlive[idx] = 0.f; hh0[idx] = __float2bfloat16(0.f); }
    if (idx < 3) out[idx] = 0.f;
}

// ---------------------------------------------------------------------------
// gemm_p: C[M,N] = act(bias + sum_s A_s @ W_s^T), W in packed fragment form.
// A row-major (LDS-staged, 64-col K-panels, double-buffered). K%64==0.
// act: 0 none, 1 relu, 2 softplus col>=32, 3 relu col<64.
// obf: 0 f32 row-major, 1 bf16 row-major, 2 bf16 packed C-frag tiles.
// Grid (N/64, M/64) x 256 thr; wave w: msub=(w&1)*32, nsub=(w>>1)*32.
// ---------------------------------------------------------------------------
__global__ __launch_bounds__(256) void gemm_p(
    const bf16* __restrict__ A0, int lda0, const bf16* __restrict__ W0p, int K0,
    const bf16* __restrict__ A1, int lda1, const bf16* __restrict__ W1p, int K1,
    const float* __restrict__ bias, int act,
    void* __restrict__ C, int ldc, int obf)
{
    __shared__ __align__(16) bf16 As[2][64][72];
    const int tid = threadIdx.x;
    const int L = tid & 63, w = tid >> 6;
    const int m0 = blockIdx.y * 64;
    const int n0 = blockIdx.x * 64;
    const int lr = L & 15, lk = (L >> 4) * 8;
    const int msub = (w & 1) * 32, nsub = (w >> 1) * 32;
    const int srow = tid >> 2, scol = (tid & 3) * 16;
    const size_t Lo = (size_t)L * 8;

    ffrag acc[2][2];
#pragma unroll
    for (int i = 0; i < 2; ++i)
#pragma unroll
        for (int j = 0; j < 2; ++j)
#pragma unroll
            for (int r = 0; r < 4; ++r) acc[i][j][r] = 0.f;

    for (int s = 0; s < 2; ++s) {
        const bf16* A = s ? A1 : A0;
        if (!A) break;
        const bf16* Wp = s ? W1p : W0p;
        const int lda = s ? lda1 : lda0;
        const int K   = s ? K1 : K0;
        const int KB = K >> 5;
        const int NP = K >> 6;
        const size_t t0 = (size_t)((n0 + nsub) >> 4);

        {   // prologue: stage panel 0 into buf 0 (coalesced 32B/thread)
            const bf16* ap = A + (size_t)(m0 + srow) * lda + scol;
            *(bfrag*)&As[0][srow][scol]     = *(const bfrag*)(ap);
            *(bfrag*)&As[0][srow][scol + 8] = *(const bfrag*)(ap + 8);
        }
        __syncthreads();

        for (int kp = 0; kp < NP; ++kp) {
            if (kp + 1 < NP) {   // stage next panel into the other buffer
                const bf16* ap = A + (size_t)(m0 + srow) * lda + (kp + 1) * 64 + scol;
                bf16* dst = &As[(kp + 1) & 1][srow][scol];
                *(bfrag*)(dst)     = *(const bfrag*)(ap);
                *(bfrag*)(dst + 8) = *(const bfrag*)(ap + 8);
            }
#pragma unroll
            for (int kbi = 0; kbi < 2; ++kbi) {
                const int kb = kp * 2 + kbi;
                bfrag b0 = *(const bfrag*)(Wp + ((t0 * KB + kb) << 9) + Lo);
                bfrag b1 = *(const bfrag*)(Wp + (((t0 + 1) * KB + kb) << 9) + Lo);
                bfrag a0 = *(const bfrag*)&As[kp & 1][msub + lr][kbi * 32 + lk];
                bfrag a1 = *(const bfrag*)&As[kp & 1][msub + 16 + lr][kbi * 32 + lk];
                acc[0][0] = __builtin_amdgcn_mfma_f32_16x16x32_bf16(a0, b0, acc[0][0], 0, 0, 0);
                acc[0][1] = __builtin_amdgcn_mfma_f32_16x16x32_bf16(a0, b1, acc[0][1], 0, 0, 0);
                acc[1][0] = __builtin_amdgcn_mfma_f32_16x16x32_bf16(a1, b0, acc[1][0], 0, 0, 0);
                acc[1][1] = __builtin_amdgcn_mfma_f32_16x16x32_bf16(a1, b1, acc[1][1], 0, 0, 0);
            }
            __syncthreads();
        }
    }

#pragma unroll
    for (int i = 0; i < 2; ++i)
#pragma unroll
    for (int j = 0; j < 2; ++j)
#pragma unroll
    for (int r = 0; r < 4; ++r) {
        const int row = m0 + msub + 16 * i + (L >> 4) * 4 + r;
        const int col = n0 + nsub + 16 * j + lr;
        float v = acc[i][j][r];
        if (bias) v += bias[col];
        if (act == 1) v = fmaxf(v, 0.f);
        else if (act == 2) { if (col >= 32) v = softplus_f(v); }
        else if (act == 3) { if (col < 64) v = fmaxf(v, 0.f); }
        if (obf == 1) {
            ((bf16*)C)[(size_t)row * ldc + col] = __float2bfloat16(v);
        } else if (obf == 2) {
            ((bf16*)C)[((size_t)(row >> 4) * (ldc >> 4) + (col >> 4)) * 256
                       + (size_t)L * 4 + r] = __float2bfloat16(v);
        } else {
            ((float*)C)[(size_t)row * ldc + col] = v;
        }
    }
}

// ---------------------------------------------------------------------------
// encmid: ONE step, stages A-C (verbatim R10, verified).
// ---------------------------------------------------------------------------
#define AST 536

__global__ __launch_bounds__(512, 1) void encmid_kernel(
    const bf16* __restrict__ e1xp,    // packed [TC*32 rt][32 ct][256]
    const float* __restrict__ eps_c,  // [TC*512,32]
    const bf16* __restrict__ ew1hp,   // packed (512x512)
    const bf16* __restrict__ ew2p,    // packed (512x512)
    const float* __restrict__ eb2,
    const bf16* __restrict__ mswp,    // packed (64x512)
    const float* __restrict__ msb,    // [64]
    const bf16* __restrict__ pzwp,    // packed (512x32)
    const float* __restrict__ pzb,    // [512]
    bf16* __restrict__ hh,            // [(TC+1)*512,512]
    float* __restrict__ emsc,         // [TC*512,64]
    bf16* __restrict__ phizc,         // [TC*512,512]
    bf16* __restrict__ pzp,           // packed phi_z a-frags [32 rt][16 kb][512]
    bf16* __restrict__ hpp,           // packed h     a-frags [32 rt][16 kb][512]
    int lt, int hsrc0)
{
    __shared__ __align__(16) bf16 hB[16][AST];
    __shared__ __align__(16) bf16 p1[16][AST];
    __shared__ __align__(16) bf16 p2[16][AST];
    __shared__ float msd[16][65];
    __shared__ __align__(16) bf16 zb[16][40];

    const int tid = threadIdx.x;
    const int L = tid & 63, w = tid >> 6;       // w in 0..7
    const int lr = L & 15, lk = (L >> 4) * 8;
    const int rq = (L >> 4) * 4;
    const int bm = blockIdx.x;
    const int m0 = bm * 16;

    const int hrow = tid >> 5, hc0 = (tid & 31) * 16;
    const size_t Lo = (size_t)L * 8;

    const size_t rb = (size_t)lt * 512 + m0;
    const size_t rt = (size_t)lt * 32 + bm;     // packed row-tile index

    // ---------- load h (bf16 from HH slot) into hB ----------
    {
        const int slot = (lt == 0) ? hsrc0 : lt;
        const bf16* hsv = hh + (size_t)slot * 262144 + (size_t)(m0 + hrow) * 512 + hc0;
        bfrag h0 = *(const bfrag*)(hsv);
        bfrag h1 = *(const bfrag*)(hsv + 8);
        *(bfrag*)&hB[hrow][hc0]     = h0;
        *(bfrag*)&hB[hrow][hc0 + 8] = h1;
        if (lt == 0 && hsrc0 != 0) {   // chunk-start h -> slot 0 for post
            bf16* d0 = hh + (size_t)(m0 + hrow) * 512 + hc0;
            *(bfrag*)(d0)     = h0;
            *(bfrag*)(d0 + 8) = h1;
        }
    }
    __syncthreads();

    // ---------- dump h a-frags for gru launch ----------
#pragma unroll
    for (int q = 0; q < 2; ++q) {
        const int kb = w * 2 + q;
        *(bfrag*)(hpp + (((size_t)bm * 16 + kb) << 9) + Lo) =
            *(const bfrag*)&hB[lr][kb * 32 + lk];
    }

    // ---------- stage A: p1 = relu(E1X + h @ eW1h^T) ----------
    {
        sfrag exv[4];
#pragma unroll
        for (int nt = 0; nt < 4; ++nt)
            exv[nt] = *(const sfrag*)(e1xp + (rt * 32 + 4 * w + nt) * 256 + (size_t)L * 4);

        bfrag wf[4][4];
#pragma unroll
        for (int d = 0; d < 4; ++d)
#pragma unroll
            for (int nt = 0; nt < 4; ++nt)
                wf[d][nt] = *(const bfrag*)(ew1hp + (((4 * w + nt) * 16 + d) << 9) + Lo);

        ffrag acc[4];
#pragma unroll
        for (int nt = 0; nt < 4; ++nt)
#pragma unroll
            for (int r = 0; r < 4; ++r) acc[nt][r] = 0.f;

#pragma unroll
        for (int kb = 0; kb < 16; ++kb) {
            bfrag a = *(const bfrag*)&hB[lr][kb * 32 + lk];
            const int cur = kb & 3;
#pragma unroll
            for (int nt = 0; nt < 4; ++nt)
                acc[nt] = __builtin_amdgcn_mfma_f32_16x16x32_bf16(a, wf[cur][nt], acc[nt], 0, 0, 0);
            if (kb < 12)
#pragma unroll
                for (int nt = 0; nt < 4; ++nt)
                    wf[cur][nt] = *(const bfrag*)(ew1hp + (((4 * w + nt) * 16 + kb + 4) << 9) + Lo);
        }
#pragma unroll
        for (int nt = 0; nt < 4; ++nt)
#pragma unroll
        for (int r = 0; r < 4; ++r) {
            const int row = rq + r, col = 64 * w + 16 * nt + lr;
            float v = acc[nt][r] + s2f(exv[nt][r]);
            p1[row][col] = __float2bfloat16(fmaxf(v, 0.f));
        }
    }
    __syncthreads();

    // ---------- stage B: p2 = relu(p1 @ eW2^T + eb2) ----------
    {
        bfrag wf[4][4];
#pragma unroll
        for (int d = 0; d < 4; ++d)
#pragma unroll
            for (int nt = 0; nt < 4; ++nt)
                wf[d][nt] = *(const bfrag*)(ew2p + (((4 * w + nt) * 16 + d) << 9) + Lo);

        ffrag acc[4];
#pragma unroll
        for (int nt = 0; nt < 4; ++nt)
#pragma unroll
            for (int r = 0; r < 4; ++r) acc[nt][r] = 0.f;

#pragma unroll
        for (int kb = 0; kb < 16; ++kb) {
            bfrag a = *(const bfrag*)&p1[lr][kb * 32 + lk];
            const int cur = kb & 3;
#pragma unroll
            for (int nt = 0; nt < 4; ++nt)
                acc[nt] = __builtin_amdgcn_mfma_f32_16x16x32_bf16(a, wf[cur][nt], acc[nt], 0, 0, 0);
            if (kb < 12)
#pragma unroll
                for (int nt = 0; nt < 4; ++nt)
                    wf[cur][nt] = *(const bfrag*)(ew2p + (((4 * w + nt) * 16 + kb + 4) << 9) + Lo);
        }
#pragma unroll
        for (int nt = 0; nt < 4; ++nt)
#pragma unroll
        for (int r = 0; r < 4; ++r) {
            const int row = rq + r, col = 64 * w + 16 * nt + lr;
            float v = fmaxf(acc[nt][r] + eb2[col], 0.f);
            p2[row][col] = __float2bfloat16(v);
        }
    }
    __syncthreads();

    // ---------- stage C1: ms = p2 @ msw^T + msb (softplus >=32) -------
    if (w < 4) {
        bfrag mf[4];
#pragma unroll
        for (int d = 0; d < 4; ++d)
            mf[d] = *(const bfrag*)(mswp + ((w * 16 + d) << 9) + Lo);
        ffrag acc;
#pragma unroll
        for (int r = 0; r < 4; ++r) acc[r] = 0.f;
#pragma unroll
        for (int kb = 0; kb < 16; ++kb) {
            bfrag a = *(const bfrag*)&p2[lr][kb * 32 + lk];
            const int cur = kb & 3;
            acc = __builtin_amdgcn_mfma_f32_16x16x32_bf16(a, mf[cur], acc, 0, 0, 0);
            if (kb < 12)
                mf[cur] = *(const bfrag*)(mswp + ((w * 16 + kb + 4) << 9) + Lo);
        }
#pragma unroll
        for (int r = 0; r < 4; ++r) {
            const int row = rq + r, col = 16 * w + lr;
            float v = acc[r] + msb[col];
            if (col >= 32) v = softplus_f(v);
            msd[row][col] = v;
            emsc[(rb + row) * 64 + col] = v;
        }
    }
    __syncthreads();

    // ---------- stage C2: z = eps*std + mean (x10 on cols<4) ----------
    {
        const int row = tid >> 5, c = tid & 31;
        float zv = eps_c[(rb + row) * 32 + c] * msd[row][32 + c] + msd[row][c];
        if (c < 4) zv *= 10.f;
        zb[row][c] = __float2bfloat16(zv);
    }
    __syncthreads();

    // ---------- stage C3: p1 = relu(z @ pzw^T + pzb) ----------
    {
        bfrag a = *(const bfrag*)&zb[lr][lk];
#pragma unroll
        for (int nt = 0; nt < 4; ++nt) {
            const int col = 64 * w + 16 * nt + lr;
            bfrag b = *(const bfrag*)(pzwp + ((4 * w + nt) << 9) + Lo);
            ffrag c_;
#pragma unroll
            for (int r = 0; r < 4; ++r) c_[r] = 0.f;
            c_ = __builtin_amdgcn_mfma_f32_16x16x32_bf16(a, b, c_, 0, 0, 0);
#pragma unroll
            for (int r = 0; r < 4; ++r) {
                const int row = rq + r;
                const float v = fmaxf(c_[r] + pzb[col], 0.f);
                p1[row][col] = __float2bfloat16(v);
            }
        }
    }
    __syncthreads();

    // ---------- dump phi_z: packed a-frags + row-major for post -------
#pragma unroll
    for (int q = 0; q < 2; ++q) {
        const int kb = w * 2 + q;
        *(bfrag*)(pzp + (((size_t)bm * 16 + kb) << 9) + Lo) =
            *(const bfrag*)&p1[lr][kb * 32 + lk];
    }
    {
        const int prow = tid >> 5, pc0 = (tid & 31) * 16;
        bf16* pp = phizc + (rb + prow) * 512 + pc0;
        *(bfrag*)(pp)     = *(const bfrag*)&p1[prow][pc0];
        *(bfrag*)(pp + 8) = *(const bfrag*)&p1[prow][pc0 + 8];
    }
}

// ---------------------------------------------------------------------------
// gru: ONE step, column-split (verbatim R10, verified).
// ---------------------------------------------------------------------------
__global__ __launch_bounds__(256) void gru_kernel(
    const bf16* __restrict__ gxxp,    // packed [TC*32 rt][96 ct][256]
    const bf16* __restrict__ wihzp,   // packed (1536x512)
    const bf16* __restrict__ whhp,    // packed (1536x512)
    const bf16* __restrict__ pzp,     // packed phi_z a-frags
    const bf16* __restrict__ hpp,     // packed h a-frags
    float* __restrict__ hlive,        // [512,512] fp32
    bf16* __restrict__ hnx,           // HH slot lt+1
    int lt)
{
    const int tid = threadIdx.x;
    const int L = tid & 63, w = tid >> 6;       // w in 0..3
    const int lr = L & 15;
    const int rq = (L >> 4) * 4;
    const int jt = blockIdx.x;                  // 0..31
    const int rt = blockIdx.y * 4 + w;          // 0..31
    const size_t Lo = (size_t)L * 8;

    // depth-2 rotated streams
    bfrag wz[2][3], wh[2][3], az2[2], ah2[2];
#pragma unroll
    for (int q = 0; q < 2; ++q) {
#pragma unroll
        for (int g = 0; g < 3; ++g) {
            wz[q][g] = *(const bfrag*)(wihzp + (((size_t)(jt + 32 * g) * 16 + q) << 9) + Lo);
            wh[q][g] = *(const bfrag*)(whhp  + (((size_t)(jt + 32 * g) * 16 + q) << 9) + Lo);
        }
        az2[q] = *(const bfrag*)(pzp + (((size_t)rt * 16 + q) << 9) + Lo);
        ah2[q] = *(const bfrag*)(hpp + (((size_t)rt * 16 + q) << 9) + Lo);
    }

    ffrag sR, sZ, aN, hN;
#pragma unroll
    for (int r = 0; r < 4; ++r) { sR[r] = 0.f; sZ[r] = 0.f; aN[r] = 0.f; hN[r] = 0.f; }

#pragma unroll
    for (int kb = 0; kb < 16; ++kb) {
        const int cur = kb & 1;
        sR = __builtin_amdgcn_mfma_f32_16x16x32_bf16(az2[cur], wz[cur][0], sR, 0, 0, 0);
        sR = __builtin_amdgcn_mfma_f32_16x16x32_bf16(ah2[cur], wh[cur][0], sR, 0, 0, 0);
        sZ = __builtin_amdgcn_mfma_f32_16x16x32_bf16(az2[cur], wz[cur][1], sZ, 0, 0, 0);
        sZ = __builtin_amdgcn_mfma_f32_16x16x32_bf16(ah2[cur], wh[cur][1], sZ, 0, 0, 0);
        aN = __builtin_amdgcn_mfma_f32_16x16x32_bf16(az2[cur], wz[cur][2], aN, 0, 0, 0);
        hN = __builtin_amdgcn_mfma_f32_16x16x32_bf16(ah2[cur], wh[cur][2], hN, 0, 0, 0);
        if (kb < 14) {
#pragma unroll
            for (int g = 0; g < 3; ++g) {
                wz[cur][g] = *(const bfrag*)(wihzp + (((size_t)(jt + 32 * g) * 16 + kb + 2) << 9) + Lo);
                wh[cur][g] = *(const bfrag*)(whhp  + (((size_t)(jt + 32 * g) * 16 + kb + 2) << 9) + Lo);
            }
            az2[cur] = *(const bfrag*)(pzp + (((size_t)rt * 16 + kb + 2) << 9) + Lo);
            ah2[cur] = *(const bfrag*)(hpp + (((size_t)rt * 16 + kb + 2) << 9) + Lo);
        }
    }

    // epilogue
    const size_t gb = ((size_t)lt * 32 + rt) * 96;
    sfrag gr = *(const sfrag*)(gxxp + (gb + jt     ) * 256 + (size_t)L * 4);
    sfrag gz = *(const sfrag*)(gxxp + (gb + jt + 32) * 256 + (size_t)L * 4);
    sfrag gn = *(const sfrag*)(gxxp + (gb + jt + 64) * 256 + (size_t)L * 4);
    const int colg = jt * 16 + lr;
#pragma unroll
    for (int r = 0; r < 4; ++r) {
        const int row = rt * 16 + rq + r;
        const size_t gidx = (size_t)row * 512 + colg;
        const float rg = sigmoid_f(s2f(gr[r]) + sR[r]);
        const float zg = sigmoid_f(s2f(gz[r]) + sZ[r]);
        const float nv = tanhf(s2f(gn[r]) + aN[r] + rg * hN[r]);
        const float hv = hlive[gidx];
        const float hnew = (1.f - zg) * nv + zg * hv;
        hlive[gidx] = hnew;
        hnx[gidx] = __float2bfloat16(hnew);
    }
}

// ---------------------------------------------------------------------------
// KLD (unchanged)
// ---------------------------------------------------------------------------
__global__ __launch_bounds__(256) void kld_kernel(
    const float* __restrict__ emsc, const float* __restrict__ pms,
    float* __restrict__ out)
{
    const size_t p0 = (size_t)blockIdx.x * 1024 + threadIdx.x;
    float acc = 0.f;
#pragma unroll
    for (int rep = 0; rep < 4; ++rep) {
        const size_t p = p0 + (size_t)rep * 256;
        const size_t i = p >> 5; const int c = p & 31;
        const float m1 = emsc[i * 64 + c];
        const float s1 = fmaxf(emsc[i * 64 + 32 + c], 1e-9f);
        const float m2 = pms[i * 64 + c];
        const float s2 = fmaxf(pms[i * 64 + 32 + c], 1e-9f);
        const float dm = m1 - m2;
        acc += 2.f * (logf(s2) - logf(s1)) + (s1 * s1 + dm * dm) / (s2 * s2) - 1.f;
    }
    for (int off = 32; off > 0; off >>= 1) acc += __shfl_down(acc, off);
    __shared__ float tmp[4];
    if ((threadIdx.x & 63) == 0) tmp[threadIdx.x >> 6] = acc;
    __syncthreads();
    if (threadIdx.x == 0)
        atomicAdd(out + 1, 0.5f * (tmp[0] + tmp[1] + tmp[2] + tmp[3]));
}

// ---------------------------------------------------------------------------
// final (unchanged)
// ---------------------------------------------------------------------------
__global__ __launch_bounds__(256) void final_kernel(
    const float* __restrict__ ddc,
    const float* __restrict__ W2,
    const float* __restrict__ b2,
    const float* __restrict__ x,
    float* __restrict__ sums,
    float* __restrict__ outDM)
{
    __shared__ float Dh[32][64];
    __shared__ float W2s[64][65];
    const int tid = threadIdx.x;
    const size_t r0 = (size_t)blockIdx.x * 32;

    for (int i = tid; i < 32 * 64; i += 256)
        Dh[i >> 6][i & 63] = ddc[(r0 + (i >> 6)) * 128 + (i & 63)];
    for (int i = tid; i < 64 * 64; i += 256) W2s[i >> 6][i & 63] = W2[i];
    __syncthreads();

    float rec = 0.f, nll = 0.f;
#pragma unroll
    for (int rep = 0; rep < 8; ++rep) {
        const int idx = rep * 256 + tid;
        const int r = idx >> 6, j = idx & 63;
        float acc = b2[j];
#pragma unroll 8
        for (int k = 0; k < 64; ++k) acc += Dh[r][k] * W2s[j][k];
        const size_t g = (r0 + r) * 64 + j;
        const float xv = x[g];
        const float sd = softplus_f(ddc[(r0 + r) * 128 + 64 + j]);
        outDM[g] = acc;
        const float d = xv - acc;
        rec += d * d;
        nll += logf(sd + 1e-5f) + 0.9189385332046727f + d * d / (2.f * sd * sd);
    }
    for (int off = 32; off > 0; off >>= 1) {
        rec += __shfl_down(rec, off);
        nll += __shfl_down(nll, off);
    }
    __shared__ float rr[4], nn[4];
    if ((tid & 63) == 0) { rr[tid >> 6] = rec; nn[tid >> 6] = nll; }
    __syncthreads();
    if (tid == 0) {
        atomicAdd(sums + 0, rr[0] + rr[1] + rr[2] + rr[3]);
        atomicAdd(sums + 2, nn[0] + nn[1] + nn[2] + nn[3]);
    }
}

// ---------------------------------------------------------------------------

static void gp(hipStream_t s, int M, int N,
               const bf16* A0, int lda0, const bf16* W0p, int K0,
               const bf16* A1, int lda1, const bf16* W1p, int K1,
               const float* bias, int act, void* C, int ldc, int obf)
{
    dim3 g(N / 64, M / 64), b(256);
    hipLaunchKernelGGL(gemm_p, g, b, 0, s,
                       A0, lda0, W0p, K0, A1, lda1, W1p, K1,
                       bias, act, C, ldc, obf);
}

static void f2b(hipStream_t s, const float* src, bf16* dst, int n) {
    hipLaunchKernelGGL(f2b_kernel, dim3((n + 255) / 256), dim3(256), 0, s, src, dst, n);
}
static void fcp(hipStream_t s, const float* src, float* dst, int n) {
    hipLaunchKernelGGL(fcopy_kernel, dim3((n + 255) / 256), dim3(256), 0, s, src, dst, n);
}
static void packw(hipStream_t s, const float* src, __hip_bfloat16* dst,
                  int ldw, int n0, int k0, int KB, int total) {
    hipLaunchKernelGGL(packw_kernel, dim3((total + 255) / 256), dim3(256), 0, s,
                       src, dst, ldw, n0, k0, KB, total);
}

// packed weight element offsets within WPK
#define P_EW1H 0
#define P_EW2  262144
#define P_MSW  524288
#define P_PZW  557056
#define P_WIHZ 573440
#define P_WHH  1359872
#define P_PXW1 2146304
#define P_PXW2 2179072
#define P_EW1X 2441216
#define P_WIHX 2703360
#define P_PRW  3489792
#define P_PMS  3751936
#define P_DW1Z 3784704
#define P_DW1H 4046848
#define P_DW2  4308992
#define P_DDW  4571136
// total 4,636,672 elems = 9,273,344 B

// Walks the SAME offset chain as the layout code (R4 crash lesson).
static size_t ws_needed(int tc) {
    size_t off = 28148736ull + (size_t)(tc + 1) * 524288ull;  // ..HPP + HH
    off += (size_t)tc * 524288ull;   // R1 / E1X
    off += (size_t)tc * 524288ull;   // R2
    off += (size_t)tc * 524288ull;   // PHIZC
    off += (size_t)tc * 131072ull;   // EMSC
    off += (size_t)tc * 262144ull;   // U
    off += (size_t)tc * 1572864ull;  // GXX
    return off;
}

extern "C" void kernel_launch(void* const* d_in, const int* in_sizes, int n_in,
                              void* d_out, int out_size, void* d_ws, size_t ws_size,
                              hipStream_t stream)
{
    const float* x_in   = (const float*)d_in[0];
    const float* eps_in = (const float*)d_in[1];
    const float* pxW1 = (const float*)d_in[2];  const float* pxb1 = (const float*)d_in[3];
    const float* pxW2 = (const float*)d_in[4];  const float* pxb2 = (const float*)d_in[5];
    const float* pzW  = (const float*)d_in[6];  const float* pzb  = (const float*)d_in[7];
    const float* eW1  = (const float*)d_in[8];  const float* eb1  = (const float*)d_in[9];
    const float* eW2  = (const float*)d_in[10]; const float* eb2  = (const float*)d_in[11];
    const float* emW  = (const float*)d_in[12]; const float* emb  = (const float*)d_in[13];
    const float* esW  = (const float*)d_in[14]; const float* esb  = (const float*)d_in[15];
    const float* prW  = (const float*)d_in[16]; const float* prb  = (const float*)d_in[17];
    const float* pmW  = (const float*)d_in[18]; const float* pmb  = (const float*)d_in[19];
    const float* psW  = (const float*)d_in[20]; const float* psb  = (const float*)d_in[21];
    const float* dW1  = (const float*)d_in[22]; const float* db1  = (const float*)d_in[23];
    const float* dW2  = (const float*)d_in[24]; const float* db2  = (const float*)d_in[25];
    const float* dsW  = (const float*)d_in[26]; const float* dsb  = (const float*)d_in[27];
    const float* dmW1 = (const float*)d_in[28]; const float* dmb1 = (const float*)d_in[29];
    const float* dmW2 = (const float*)d_in[30]; const float* dmb2 = (const float*)d_in[31];
    const float* gWih = (const float*)d_in[32]; const float* gWhh = (const float*)d_in[33];

    float* out = (float*)d_out;
    char* ws = (char*)d_ws;

    int TC = 1;
    const int cands[9] = {256, 128, 64, 32, 16, 8, 4, 2, 1};
    for (int i = 0; i < 9; ++i)
        if (ws_needed(cands[i]) <= ws_size) { TC = cands[i]; break; }
    const int NCH = 256 / TC;

    // ---- workspace map ----
    bf16*  WPK   = (bf16*)(ws);                         // 9,273,344 B
    float* BB    = (float*)(ws + 9273344ull);           // 1,024 B
    bf16*  XBF   = (bf16*)(ws + 9274368ull);            // 16,777,216 B
    float* HLIVE = (float*)(ws + 26051584ull);          // 1,048,576 B
    bf16*  PZP   = (bf16*)(ws + 27100160ull);           // 524,288 B
    bf16*  HPP   = (bf16*)(ws + 27624448ull);           // 524,288 B
    bf16*  HH    = (bf16*)(ws + 28148736ull);           // (TC+1)*524,288 B
    size_t off = 28148736ull + (size_t)(TC + 1) * 524288ull;
    bf16*  R1    = (bf16*)(ws + off); off += (size_t)TC * 524288ull;   // also E1X
    bf16*  R2    = (bf16*)(ws + off); off += (size_t)TC * 524288ull;   // PHIX / DECH
    bf16*  PHIZC = (bf16*)(ws + off); off += (size_t)TC * 524288ull;
    float* EMSC  = (float*)(ws + off); off += (size_t)TC * 131072ull;
    float* U     = (float*)(ws + off); off += (size_t)TC * 262144ull;  // PMS then DDC
    bf16*  GXX   = (bf16*)(ws + off);                   // TC*1,572,864 B

    // ---- setup: conversions + packing (all weights -> packed frags) ----
    f2b(stream, x_in, XBF, 8388608);
    fcp(stream, emb,  BB + 0,   32);
    fcp(stream, esb,  BB + 32,  32);
    fcp(stream, pmb,  BB + 64,  32);
    fcp(stream, psb,  BB + 96,  32);
    fcp(stream, dmb1, BB + 128, 64);
    fcp(stream, dsb,  BB + 192, 64);

    packw(stream, eW1,  WPK + P_EW1H, 1024, 0, 512, 16, 262144);
    packw(stream, eW2,  WPK + P_EW2,   512, 0,   0, 16, 262144);
    packw(stream, emW,  WPK + P_MSW,   512, 0,   0, 16, 16384);
    packw(stream, esW,  WPK + P_MSW + 16384, 512, 0, 0, 16, 16384);
    packw(stream, pzW,  WPK + P_PZW,    32, 0,   0,  1, 16384);
    packw(stream, gWih, WPK + P_WIHZ, 1024, 0, 512, 16, 786432);
    packw(stream, gWhh, WPK + P_WHH,   512, 0,   0, 16, 786432);
    packw(stream, pxW1, WPK + P_PXW1,   64, 0,   0,  2, 32768);
    packw(stream, pxW2, WPK + P_PXW2,  512, 0,   0, 16, 262144);
    packw(stream, eW1,  WPK + P_EW1X, 1024, 0,   0, 16, 262144);
    packw(stream, gWih, WPK + P_WIHX, 1024, 0,   0, 16, 786432);
    packw(stream, prW,  WPK + P_PRW,   512, 0,   0, 16, 262144);
    packw(stream, pmW,  WPK + P_PMS,   512, 0,   0, 16, 16384);
    packw(stream, psW,  WPK + P_PMS + 16384, 512, 0, 0, 16, 16384);
    packw(stream, dW1,  WPK + P_DW1Z, 1024, 0,   0, 16, 262144);
    packw(stream, dW1,  WPK + P_DW1H, 1024, 0, 512, 16, 262144);
    packw(stream, dW2,  WPK + P_DW2,   512, 0,   0, 16, 262144);
    packw(stream, dmW1, WPK + P_DDW,   512, 0,   0, 16, 32768);
    packw(stream, dsW,  WPK + P_DDW + 32768, 512, 0, 0, 16, 32768);

    hipLaunchKernelGGL(init_kernel, dim3(1024), dim3(256), 0, stream,
                       HLIVE, HH, out);

    for (int c = 0; c < NCH; ++c) {
        const int cs = c * TC;
        const int MR = TC * 512;

        // ---- pre: phi_x MLP for the chunk ----
        gp(stream, MR, 512, XBF + (size_t)cs * 32768, 64, WPK + P_PXW1, 64,
           nullptr, 0, nullptr, 0, pxb1, 1, R1, 512, 1);
        gp(stream, MR, 512, R1, 512, WPK + P_PXW2, 512,
           nullptr, 0, nullptr, 0, pxb2, 1, R2, 512, 1);

        // ---- pre: hoisted phi_x contributions (packed C-fragment out) ----
        gp(stream, MR, 512, R2, 512, WPK + P_EW1X, 512,
           nullptr, 0, nullptr, 0, eb1, 0, R1, 512, 2);
        gp(stream, MR, 1536, R2, 512, WPK + P_WIHX, 512,
           nullptr, 0, nullptr, 0, nullptr, 0, GXX, 1536, 2);

        // ---- sequential steps: 2 launches each, no fences ----
        for (int lt = 0; lt < TC; ++lt) {
            hipLaunchKernelGGL(encmid_kernel, dim3(32), dim3(512), 0, stream,
                               R1, eps_in + (size_t)cs * 16384,
                               WPK + P_EW1H, WPK + P_EW2, eb2,
                               WPK + P_MSW, BB, WPK + P_PZW, pzb,
                               HH, EMSC, PHIZC, PZP, HPP,
                               lt, (c == 0) ? 0 : TC);
            hipLaunchKernelGGL(gru_kernel, dim3(32, 8), dim3(256), 0, stream,
                               GXX, WPK + P_WIHZ, WPK + P_WHH, PZP, HPP,
                               HLIVE, HH + (size_t)(lt + 1) * 262144, lt);
        }

        // ---- post: prior + KLD ----
        gp(stream, MR, 512, HH, 512, WPK + P_PRW, 512,
           nullptr, 0, nullptr, 0, prb, 1, R1, 512, 1);
        gp(stream, MR, 64, R1, 512, WPK + P_PMS, 512,
           nullptr, 0, nullptr, 0, BB + 64, 2, U, 64, 0);
        hipLaunchKernelGGL(kld_kernel, dim3(TC * 16), dim3(256), 0, stream,
                           EMSC, U, out);

        // ---- post: dec + NLL/rec ----
        gp(stream, MR, 512, PHIZC, 512, WPK + P_DW1Z, 512,
           HH, 512, WPK + P_DW1H, 512, db1, 1, R1, 512, 1);
        gp(stream, MR, 512, R1, 512, WPK + P_DW2, 512,
           nullptr, 0, nullptr, 0, db2, 1, R2, 512, 1);               // R2: PHIX dead
        gp(stream, MR, 128, R2, 512, WPK + P_DDW, 512,
           nullptr, 0, nullptr, 0, BB + 128, 3, U, 128, 0);
        hipLaunchKernelGGL(final_kernel, dim3(MR / 32), dim3(256), 0, stream,
                           U, dmW2, dmb2, x_in + (size_t)cs * 32768,
                           out, out + 3 + (size_t)cs * 32768);
    }
}